// Round 4
// baseline (14976.675 us; speedup 1.0000x reference)
//
#include <hip/hip_runtime.h>
#include <hip/hip_bf16.h>
#include <stdint.h>

#define T_STEPS 16
#define NN      20000
#define M_PAD   20032     // 313 * 64
#define NBLK    313
#define EE      640000
#define FF      64
#define HH      128
#define CC      16
#define BN_EPS  1e-5f

typedef __hip_bfloat16 bf16;
typedef __attribute__((ext_vector_type(8))) short short8;
typedef __attribute__((ext_vector_type(4))) float f32x4;

__device__ __forceinline__ float rdf(const void* p, long i, int isbf){
  return isbf ? __bfloat162float(((const bf16*)p)[i]) : ((const float*)p)[i];
}
__device__ __forceinline__ ushort f2bu(float f){
  bf16 h = __float2bfloat16(f);
  return *reinterpret_cast<ushort*>(&h);
}
__device__ __forceinline__ float bu2f(ushort u){
  bf16 h; *reinterpret_cast<ushort*>(&h) = u;
  return __bfloat162float(h);
}

// ---------------- dtype probe (flag=1 iff buffers are bf16) ----------------
__global__ void k_detect(const void* x, int* flag){
  __shared__ int sh[256];
  int tid = threadIdx.x;
  const uint16_t* u = (const uint16_t*)x;
  uint16_t v = u[2*tid];
  int e = (v >> 7) & 0xFF;
  sh[tid] = (e >= 120 && e <= 134) ? 1 : 0;
  __syncthreads();
  for (int o = 128; o; o >>= 1){ if (tid < o) sh[tid] += sh[tid+o]; __syncthreads(); }
  if (tid == 0) flag[0] = (sh[0] >= 128) ? 1 : 0;
}

// ---------------- graph setup ----------------
__global__ void k_init(float* deg, int* cnt, int* cursor, int n){
  int i = blockIdx.x*blockDim.x + threadIdx.x;
  if (i < n){ deg[i] = 1.0f; cnt[i] = 0; cursor[i] = 0; }
}
__global__ void k_deg(const int* src, const int* dst, const void* w,
                      float* deg, int* cnt, int e, const int* flag){
  int i = blockIdx.x*blockDim.x + threadIdx.x;
  if (i < e){
    int d = dst[i];
    atomicAdd(&deg[d], rdf(w, i, *flag));
    atomicAdd(&cnt[d], 1);
  }
}
__global__ void k_dinv(const float* deg, float* dinv, float* selfnorm, int n){
  int i = blockIdx.x*blockDim.x + threadIdx.x;
  if (i < n){
    float d = deg[i];
    float r = d > 0.f ? rsqrtf(d) : 0.f;
    dinv[i] = r; selfnorm[i] = r*r;
  }
}
__global__ void k_scan(const int* cnt, int* offs, int n){
  __shared__ int part[256];
  int tid = threadIdx.x;
  int chunk = (n + 255)/256;
  int lo = tid*chunk; int hi = lo + chunk;
  if (hi > n) hi = n;
  if (lo > n) lo = n;
  int s = 0;
  for (int i = lo; i < hi; i++) s += cnt[i];
  part[tid] = s;
  __syncthreads();
  for (int off = 1; off < 256; off <<= 1){
    int t = (tid >= off) ? part[tid-off] : 0;
    __syncthreads();
    part[tid] += t;
    __syncthreads();
  }
  int run = part[tid] - s;
  for (int i = lo; i < hi; i++){ offs[i] = run; run += cnt[i]; }
  if (tid == 255) offs[n] = part[255];
}
__global__ void k_fill(const int* src, const int* dst, const void* w, const float* dinv,
                       const int* offs, int* cursor, int* csr_src, float* csr_norm, int e,
                       const int* flag){
  int i = blockIdx.x*blockDim.x + threadIdx.x;
  if (i < e){
    int s = src[i], d = dst[i];
    int pos = offs[d] + atomicAdd(&cursor[d], 1);
    csr_src[pos]  = s;
    csr_norm[pos] = dinv[s] * rdf(w, i, *flag) * dinv[d];
  }
}

__global__ void k_cvt(const void* src, long off, float* dst, int n, const int* flag){
  int i = blockIdx.x*blockDim.x + threadIdx.x;
  if (i < n) dst[i] = rdf(src, off + i, *flag);
}
__global__ void k_zero(float* p, int n){
  int i = blockIdx.x*blockDim.x + threadIdx.x;
  if (i < n) p[i] = 0.f;
}

// ---------------- weight swizzle into MFMA B-fragment order ----------------
// b-frag for (ks, ct): lane l, elem j <- B[ks*32 + 8*(l>>4)+j][ct*16 + (l&15)]
// stored at dst[((ks*NCT + ct)*64 + l)*8 + j]
// mode 0: B = src1 [K,N] row-major (flag dtype)
// mode 1: GRU cat: K=256, N=512; src1=Wih[384,128], src2=Whh[384,128]
__global__ void k_swz(const void* s1, const void* s2, ushort* dst,
                      int K, int N, int mode, const int* flag){
  int total = (K/32)*(N/16)*512;
  int o = blockIdx.x*blockDim.x + threadIdx.x;
  if (o >= total) return;
  int nct = N/16;
  int ks = o / (nct*512);
  int r1 = o % (nct*512);
  int ct = r1 / 512;
  int r2 = r1 % 512;
  int l  = r2 >> 3;
  int j  = r2 & 7;
  int k  = ks*32 + ((l>>4)<<3) + j;
  int c  = ct*16 + (l&15);
  float v;
  int isbf = *flag;
  if (mode == 0){
    v = rdf(s1, (long)k*N + c, isbf);
  } else {
    if (k < HH){
      if (c < 2*HH)      v = rdf(s1, (long)c*HH + k, isbf);          // r,z from Wih
      else if (c < 3*HH) v = rdf(s1, (long)c*HH + k, isbf);          // i_n from Wih
      else               v = 0.f;                                     // h_n x-part
    } else {
      int kh = k - HH;
      if (c < 2*HH)      v = rdf(s2, (long)c*HH + kh, isbf);         // r,z from Whh
      else if (c < 3*HH) v = 0.f;                                     // i_n h-part
      else               v = rdf(s2, (long)(c-HH)*HH + kh, isbf);    // h_n from Whh
    }
  }
  dst[o] = f2bu(v);
}

// bias4[c]: c<256: bih[c]+bhh[c]; c<384: bih[c]; else bhh[c-128]
__global__ void k_bias4(const void* bih, const void* bhh, float* bias4, const int* flag){
  int c = blockIdx.x*blockDim.x + threadIdx.x;
  if (c >= 4*HH) return;
  int isbf = *flag;
  float v;
  if (c < 2*HH)      v = rdf(bih, c, isbf) + rdf(bhh, c, isbf);
  else if (c < 3*HH) v = rdf(bih, c, isbf);
  else               v = rdf(bhh, c - HH, isbf);
  bias4[c] = v;
}

// ---------------- MFMA GEMM, N=128, BM=64 tile, 4 waves ----------------
// MODE 0: A = x_seq (flag dtype, offset aoff), +bias +relu        (G1, K=64)
// MODE 1: A = bf16 plain                                          (G2, K=128)
// MODE 2: A = bf16 agg, affine(scale,shift)+relu at load          (G3, K=128)
template<int MODE, int K>
__global__ __launch_bounds__(256) void k_mgemm(const void* A, long aoff, const int* flag,
    const float* bias, const float* scale, const float* shift,
    const short8* Bsw, ushort* out)
{
  __shared__ __align__(16) ushort As[64*(K+8)];
  const int tid = threadIdx.x;
  const int bm  = blockIdx.x * 64;
  {
    const int KQ = K/4;
    int row = tid >> 2, kq = tid & 3;
    int grow = bm + row;
    ushort* dst = &As[row*(K+8) + kq*KQ];
    if (MODE == 0){
      if (grow < NN){
        if (*flag){
          const ushort* s = (const ushort*)A + aoff + (long)grow*K + kq*KQ;
          for (int j=0;j<KQ;j++) dst[j] = s[j];
        } else {
          const float* s = (const float*)A + aoff + (long)grow*K + kq*KQ;
          for (int j=0;j<KQ;j++) dst[j] = f2bu(s[j]);
        }
      } else {
        for (int j=0;j<KQ;j++) dst[j] = 0;
      }
    } else if (MODE == 1){
      const ushort* s = (const ushort*)A + (long)grow*K + kq*KQ;
      for (int j=0;j<KQ;j++) dst[j] = s[j];
    } else {
      const ushort* s = (const ushort*)A + (long)grow*K + kq*KQ;
      for (int j=0;j<KQ;j++){
        int k = kq*KQ + j;
        float v = bu2f(s[j])*scale[k] + shift[k];
        dst[j] = f2bu(fmaxf(v, 0.f));
      }
    }
  }
  __syncthreads();
  const int w = tid >> 6, l = tid & 63;
  f32x4 acc[4][2];
  #pragma unroll
  for (int i=0;i<4;i++)
    #pragma unroll
    for (int j=0;j<2;j++) acc[i][j] = (f32x4){0.f,0.f,0.f,0.f};
  #pragma unroll
  for (int ks=0; ks<K/32; ks++){
    short8 a[4], b[2];
    #pragma unroll
    for (int rt=0;rt<4;rt++)
      a[rt] = *reinterpret_cast<const short8*>(&As[(rt*16 + (l&15))*(K+8) + ks*32 + ((l>>4)<<3)]);
    #pragma unroll
    for (int c2=0;c2<2;c2++)
      b[c2] = Bsw[(ks*8 + (w*2+c2))*64 + l];
    #pragma unroll
    for (int rt=0;rt<4;rt++)
      #pragma unroll
      for (int c2=0;c2<2;c2++)
        acc[rt][c2] = __builtin_amdgcn_mfma_f32_16x16x32_bf16(a[rt], b[c2], acc[rt][c2], 0,0,0);
  }
  #pragma unroll
  for (int rt=0;rt<4;rt++)
    #pragma unroll
    for (int c2=0;c2<2;c2++){
      int col = w*32 + c2*16 + (l&15);
      #pragma unroll
      for (int reg=0;reg<4;reg++){
        int grow = bm + rt*16 + ((l>>4)<<2) + reg;
        float v = acc[rt][c2][reg];
        if (MODE==0) v = fmaxf(v + bias[col], 0.f);
        out[(long)grow*HH + col] = f2bu(v);
      }
    }
}

// ---------------- fused GRU step: [x|h]@[256,512] -> gates -> h ----------------
// XMODE 0: x = bf16 agg + affine+relu (GRU layer 0)
// XMODE 1: x = fp32 plain (GRU layer 1, x = h0)
template<int XMODE>
__global__ __launch_bounds__(256) void k_mgru(const void* xsrc, const float* hprev,
    const float* scale, const float* shift,
    const short8* Bsw, const float* bias4, float* hout)
{
  __shared__ __align__(16) ushort As[64*264];
  const int tid = threadIdx.x;
  const int bm = blockIdx.x*64;
  {
    int row = tid>>2, kq = tid&3;
    int grow = bm + row;
    ushort* dst = &As[row*264 + kq*64];
    if (kq < 2){
      if (XMODE==0){
        const ushort* s = (const ushort*)xsrc + (long)grow*HH + kq*64;
        for (int j=0;j<64;j++){
          int k = kq*64 + j;
          float v = bu2f(s[j])*scale[k] + shift[k];
          dst[j] = f2bu(fmaxf(v,0.f));
        }
      } else {
        const float* s = (const float*)xsrc + (long)grow*HH + kq*64;
        for (int j=0;j<64;j++) dst[j] = f2bu(s[j]);
      }
    } else {
      const float* s = hprev + (long)grow*HH + (kq-2)*64;
      for (int j=0;j<64;j++) dst[j] = f2bu(s[j]);
    }
  }
  __syncthreads();
  const int w = tid>>6, l = tid&63;
  f32x4 acc[4][4][2];   // [row-tile][gate][col-half]
  #pragma unroll
  for (int i=0;i<4;i++)
    #pragma unroll
    for (int g=0;g<4;g++)
      #pragma unroll
      for (int j=0;j<2;j++) acc[i][g][j] = (f32x4){0.f,0.f,0.f,0.f};
  for (int ks=0; ks<8; ks++){
    short8 a[4];
    #pragma unroll
    for (int rt=0;rt<4;rt++)
      a[rt] = *reinterpret_cast<const short8*>(&As[(rt*16 + (l&15))*264 + ks*32 + ((l>>4)<<3)]);
    #pragma unroll
    for (int g=0;g<4;g++){
      short8 b[2];
      #pragma unroll
      for (int c2=0;c2<2;c2++)
        b[c2] = Bsw[(ks*32 + (g*8 + w*2 + c2))*64 + l];
      #pragma unroll
      for (int rt=0;rt<4;rt++)
        #pragma unroll
        for (int c2=0;c2<2;c2++)
          acc[rt][g][c2] = __builtin_amdgcn_mfma_f32_16x16x32_bf16(a[rt], b[c2], acc[rt][g][c2], 0,0,0);
    }
  }
  // epilogue: gates -> hnew
  #pragma unroll
  for (int rt=0;rt<4;rt++)
    #pragma unroll
    for (int c2=0;c2<2;c2++){
      int col = w*32 + c2*16 + (l&15);
      float br = bias4[col], bz = bias4[HH+col], bi = bias4[2*HH+col], bh = bias4[3*HH+col];
      #pragma unroll
      for (int reg=0;reg<4;reg++){
        int grow = bm + rt*16 + ((l>>4)<<2) + reg;
        float rp = acc[rt][0][c2][reg] + br;
        float zp = acc[rt][1][c2][reg] + bz;
        float ip = acc[rt][2][c2][reg] + bi;
        float hp = acc[rt][3][c2][reg] + bh;
        float r = 1.f/(1.f + expf(-rp));
        float z = 1.f/(1.f + expf(-zp));
        float nc = tanhf(ip + r*hp);
        float hv = hprev[(long)grow*HH + col];
        hout[(long)grow*HH + col] = (1.f - z)*nc + z*hv;
      }
    }
}

// ---------------- conv (CSR gather) + fused BN partial stats ----------------
__global__ __launch_bounds__(256) void k_conv(const ushort* in, ushort* out,
    const int* offs, const int* csr_src, const float* csr_norm,
    const float* selfn, float* sums)
{
  int tid = threadIdx.x;
  int h = tid & 127;
  int n0 = blockIdx.x*64 + (tid >> 7)*32;
  float s = 0.f, ss = 0.f;
  for (int i = 0; i < 32; i++){
    int n = n0 + i;
    if (n >= NN) break;
    float acc = selfn[n] * bu2f(in[(long)n*HH + h]);
    int e0 = offs[n], e1 = offs[n+1];
    for (int e = e0; e < e1; e++)
      acc += csr_norm[e] * bu2f(in[(long)csr_src[e]*HH + h]);
    out[(long)n*HH + h] = f2bu(acc);
    s += acc; ss += acc*acc;
  }
  atomicAdd(&sums[h], s);
  atomicAdd(&sums[HH+h], ss);
}

// ---------------- BN finalize: sums -> scale/shift; re-zero sums ----------------
__global__ void k_fin(float* sums, const void* g, const void* be,
                      float* scale, float* shift, const int* flag){
  int h = threadIdx.x;
  if (h >= HH) return;
  float inv_n = 1.0f/(float)NN;
  float mu  = sums[h]*inv_n;
  float var = fmaxf(sums[HH+h]*inv_n - mu*mu, 0.f);
  float sc  = rdf(g, h, *flag) * rsqrtf(var + BN_EPS);
  scale[h] = sc;
  shift[h] = rdf(be, h, *flag) - mu*sc;
  sums[h] = 0.f; sums[HH+h] = 0.f;
}

// ---------------- output head ----------------
__global__ void k_out(const float* h, const float* Wo, const float* bo, void* out, int n,
                      const int* flag){
  __shared__ float Ws[HH][CC+1];
  __shared__ float bs[CC];
  int tid = threadIdx.x;
  for (int i = tid; i < HH*CC; i += 256) Ws[i/CC][i%CC] = Wo[i];
  if (tid < CC) bs[tid] = bo[tid];
  __syncthreads();
  int row = blockIdx.x*16 + (tid >> 4);
  int c   = tid & 15;
  if (row >= n) return;
  const float* hr = h + (size_t)row*HH;
  float s = bs[c];
  #pragma unroll 8
  for (int j = 0; j < HH; j++) s += hr[j]*Ws[j][c];
  float m = s;
  for (int o = 8; o; o >>= 1) m = fmaxf(m, __shfl_xor(m, o, 16));
  float e = expf(s - m);
  float sum = e;
  for (int o = 8; o; o >>= 1) sum += __shfl_xor(sum, o, 16);
  float v = s - m - logf(sum);
  size_t idx = (size_t)row*CC + c;
  if (*flag) ((bf16*)out)[idx] = __float2bfloat16(v);
  else       ((float*)out)[idx] = v;
}

// ---------------- launcher ----------------
static inline size_t alignup(size_t x){ return (x + 255) & ~(size_t)255; }
static inline int ceil_div(int a, int b){ return (a + b - 1)/b; }

extern "C" void kernel_launch(void* const* d_in, const int* in_sizes, int n_in,
                              void* d_out, int out_size, void* d_ws, size_t ws_size,
                              hipStream_t stream){
  const void* x_seq = d_in[0];
  const int*  eidx  = (const int*)d_in[1];
  const void* ew    = d_in[2];
  const void* W_in  = d_in[3];
  const void* b_in  = d_in[4];
  const void* W1    = d_in[5];
  // d_in[6] = bc1 : cancels under training-mode BN
  const void* g1    = d_in[7];
  const void* be1   = d_in[8];
  const void* W2    = d_in[9];
  // d_in[10] = bc2 : cancels under BN
  const void* g2    = d_in[11];
  const void* be2   = d_in[12];
  const void* Wih0  = d_in[13];
  const void* Whh0  = d_in[14];
  const void* bih0  = d_in[15];
  const void* bhh0  = d_in[16];
  const void* Wih1  = d_in[17];
  const void* Whh1  = d_in[18];
  const void* bih1  = d_in[19];
  const void* bhh1  = d_in[20];
  const void* W_out = d_in[21];
  const void* b_out = d_in[22];
  const int* src = eidx;
  const int* dst = eidx + EE;

  // workspace (~48 MB)
  char* p = (char*)d_ws;
  auto alloc = [&](size_t bytes)->void*{ void* r = (void*)p; p += alignup(bytes); return r; };
  int*   flag     = (int*)  alloc(4);
  float* deg      = (float*)alloc(NN*4);
  float* dinv     = (float*)alloc(NN*4);
  float* selfn    = (float*)alloc(NN*4);
  int*   cnt      = (int*)  alloc(NN*4);
  int*   cursor   = (int*)  alloc(NN*4);
  int*   offs     = (int*)  alloc((NN+1)*4);
  int*   csr_src  = (int*)  alloc((size_t)EE*4);
  float* csr_norm = (float*)alloc((size_t)EE*4);
  ushort* B1sw  = (ushort*)alloc((size_t)(FF/32)*(HH/16)*512*2);      // 16 KB
  ushort* B2sw  = (ushort*)alloc((size_t)(HH/32)*(HH/16)*512*2);      // 32 KB
  ushort* B3sw  = (ushort*)alloc((size_t)(HH/32)*(HH/16)*512*2);
  ushort* BG0sw = (ushort*)alloc((size_t)8*32*512*2);                 // 256 KB
  ushort* BG1sw = (ushort*)alloc((size_t)8*32*512*2);
  float* bias4_0 = (float*)alloc(4*HH*4);
  float* bias4_1 = (float*)alloc(4*HH*4);
  float* b_inF   = (float*)alloc(HH*4);
  float* W_outF  = (float*)alloc(HH*CC*4);
  float* b_outF  = (float*)alloc(CC*4);
  float* scale1  = (float*)alloc(HH*4);
  float* shift1  = (float*)alloc(HH*4);
  float* scale2  = (float*)alloc(HH*4);
  float* shift2  = (float*)alloc(HH*4);
  float* sums    = (float*)alloc(2*HH*4);
  ushort* temp1b = (ushort*)alloc((size_t)M_PAD*HH*2);  // 5.13 MB
  ushort* temp2b = (ushort*)alloc((size_t)M_PAD*HH*2);
  ushort* agg1b  = (ushort*)alloc((size_t)M_PAD*HH*2);
  ushort* agg2b  = (ushort*)alloc((size_t)M_PAD*HH*2);
  float*  h0buf  = (float*)alloc((size_t)M_PAD*HH*4);   // 10.26 MB
  float*  h1buf  = (float*)alloc((size_t)M_PAD*HH*4);
  (void)ws_size; (void)n_in; (void)in_sizes; (void)out_size;

  const int TPB = 256;
  // ---- dtype probe + graph setup ----
  k_detect<<<1, 256, 0, stream>>>(x_seq, flag);
  k_init<<<ceil_div(NN,TPB), TPB, 0, stream>>>(deg, cnt, cursor, NN);
  k_deg <<<ceil_div(EE,TPB), TPB, 0, stream>>>(src, dst, ew, deg, cnt, EE, flag);
  k_dinv<<<ceil_div(NN,TPB), TPB, 0, stream>>>(deg, dinv, selfn, NN);
  k_scan<<<1, 256, 0, stream>>>(cnt, offs, NN);
  k_fill<<<ceil_div(EE,TPB), TPB, 0, stream>>>(src, dst, ew, dinv, offs, cursor, csr_src, csr_norm, EE, flag);

  // ---- weight prep ----
  k_swz<<<ceil_div(2*8*512,TPB), TPB, 0, stream>>>(W_in, nullptr, B1sw, FF, HH, 0, flag);
  k_swz<<<ceil_div(4*8*512,TPB), TPB, 0, stream>>>(W1,   nullptr, B2sw, HH, HH, 0, flag);
  k_swz<<<ceil_div(4*8*512,TPB), TPB, 0, stream>>>(W2,   nullptr, B3sw, HH, HH, 0, flag);
  k_swz<<<ceil_div(8*32*512,TPB), TPB, 0, stream>>>(Wih0, Whh0, BG0sw, 2*HH, 4*HH, 1, flag);
  k_swz<<<ceil_div(8*32*512,TPB), TPB, 0, stream>>>(Wih1, Whh1, BG1sw, 2*HH, 4*HH, 1, flag);
  k_bias4<<<2, 256, 0, stream>>>(bih0, bhh0, bias4_0, flag);
  k_bias4<<<2, 256, 0, stream>>>(bih1, bhh1, bias4_1, flag);
  k_cvt<<<1, 128, 0, stream>>>(b_in, 0, b_inF, HH, flag);
  k_cvt<<<ceil_div(HH*CC,TPB), TPB, 0, stream>>>(W_out, 0, W_outF, HH*CC, flag);
  k_cvt<<<1, CC, 0, stream>>>(b_out, 0, b_outF, CC, flag);
  int totH = M_PAD*HH;
  k_zero<<<ceil_div(totH,TPB), TPB, 0, stream>>>(h0buf, totH);
  k_zero<<<ceil_div(totH,TPB), TPB, 0, stream>>>(h1buf, totH);
  k_zero<<<1, 256, 0, stream>>>(sums, 2*HH);

  // ---- main temporal loop ----
  for (int t = 0; t < T_STEPS; t++){
    long aoff = (long)t*NN*FF;
    k_mgemm<0,FF><<<NBLK, 256, 0, stream>>>(x_seq, aoff, flag, b_inF, nullptr, nullptr,
                                            (const short8*)B1sw, temp1b);
    k_mgemm<1,HH><<<NBLK, 256, 0, stream>>>(temp1b, 0, flag, nullptr, nullptr, nullptr,
                                            (const short8*)B2sw, temp2b);
    k_conv<<<NBLK, 256, 0, stream>>>(temp2b, agg1b, offs, csr_src, csr_norm, selfn, sums);
    k_fin<<<1, 128, 0, stream>>>(sums, g1, be1, scale1, shift1, flag);
    k_mgemm<2,HH><<<NBLK, 256, 0, stream>>>(agg1b, 0, flag, nullptr, scale1, shift1,
                                            (const short8*)B3sw, temp2b);
    k_conv<<<NBLK, 256, 0, stream>>>(temp2b, agg2b, offs, csr_src, csr_norm, selfn, sums);
    k_fin<<<1, 128, 0, stream>>>(sums, g2, be2, scale2, shift2, flag);
    k_mgru<0><<<NBLK, 256, 0, stream>>>(agg2b, h0buf, scale2, shift2,
                                        (const short8*)BG0sw, bias4_0, h0buf);
    k_mgru<1><<<NBLK, 256, 0, stream>>>(h0buf, h1buf, nullptr, nullptr,
                                        (const short8*)BG1sw, bias4_1, h1buf);
  }

  // ---- output head ----
  k_out<<<ceil_div(NN,16), 256, 0, stream>>>(h1buf, W_outF, b_outF, d_out, NN, flag);
}

// Round 5
// 3690.349 us; speedup vs baseline: 4.0583x; 4.0583x over previous
//
#include <hip/hip_runtime.h>
#include <hip/hip_bf16.h>
#include <stdint.h>

#define T_STEPS 16
#define NN      20000
#define M_PAD   20032     // 313 * 64
#define NBLK    313
#define EE      640000
#define FF      64
#define HH      128
#define CC      16
#define BN_EPS  1e-5f

typedef __hip_bfloat16 bf16;
typedef __attribute__((ext_vector_type(8))) short short8;
typedef __attribute__((ext_vector_type(4))) float f32x4;

union V8 { short8 v; ushort u[8]; };

__device__ __forceinline__ float rdf(const void* p, long i, int isbf){
  return isbf ? __bfloat162float(((const bf16*)p)[i]) : ((const float*)p)[i];
}
__device__ __forceinline__ ushort f2bu(float f){
  bf16 h = __float2bfloat16(f);
  return *reinterpret_cast<ushort*>(&h);
}
__device__ __forceinline__ float bu2f(ushort u){
  bf16 h; *reinterpret_cast<ushort*>(&h) = u;
  return __bfloat162float(h);
}

// ---------------- dtype probe (flag=1 iff buffers are bf16) ----------------
__global__ void k_detect(const void* x, int* flag){
  __shared__ int sh[256];
  int tid = threadIdx.x;
  const uint16_t* u = (const uint16_t*)x;
  uint16_t v = u[2*tid];
  int e = (v >> 7) & 0xFF;
  sh[tid] = (e >= 120 && e <= 134) ? 1 : 0;
  __syncthreads();
  for (int o = 128; o; o >>= 1){ if (tid < o) sh[tid] += sh[tid+o]; __syncthreads(); }
  if (tid == 0) flag[0] = (sh[0] >= 128) ? 1 : 0;
}

// ---------------- graph setup ----------------
__global__ void k_init(float* deg, int* cnt, int* cursor, int n){
  int i = blockIdx.x*blockDim.x + threadIdx.x;
  if (i < n){ deg[i] = 1.0f; cnt[i] = 0; cursor[i] = 0; }
}
__global__ void k_deg(const int* src, const int* dst, const void* w,
                      float* deg, int* cnt, int e, const int* flag){
  int i = blockIdx.x*blockDim.x + threadIdx.x;
  if (i < e){
    int d = dst[i];
    atomicAdd(&deg[d], rdf(w, i, *flag));
    atomicAdd(&cnt[d], 1);
  }
}
__global__ void k_dinv(const float* deg, float* dinv, float* selfnorm, int n){
  int i = blockIdx.x*blockDim.x + threadIdx.x;
  if (i < n){
    float d = deg[i];
    float r = d > 0.f ? rsqrtf(d) : 0.f;
    dinv[i] = r; selfnorm[i] = r*r;
  }
}
__global__ void k_scan(const int* cnt, int* offs, int n){
  __shared__ int part[256];
  int tid = threadIdx.x;
  int chunk = (n + 255)/256;
  int lo = tid*chunk; int hi = lo + chunk;
  if (hi > n) hi = n;
  if (lo > n) lo = n;
  int s = 0;
  for (int i = lo; i < hi; i++) s += cnt[i];
  part[tid] = s;
  __syncthreads();
  for (int off = 1; off < 256; off <<= 1){
    int t = (tid >= off) ? part[tid-off] : 0;
    __syncthreads();
    part[tid] += t;
    __syncthreads();
  }
  int run = part[tid] - s;
  for (int i = lo; i < hi; i++){ offs[i] = run; run += cnt[i]; }
  if (tid == 255) offs[n] = part[255];
}
__global__ void k_fill(const int* src, const int* dst, const void* w, const float* dinv,
                       const int* offs, int* cursor, int* csr_src, float* csr_norm, int e,
                       const int* flag){
  int i = blockIdx.x*blockDim.x + threadIdx.x;
  if (i < e){
    int s = src[i], d = dst[i];
    int pos = offs[d] + atomicAdd(&cursor[d], 1);
    csr_src[pos]  = s;
    csr_norm[pos] = dinv[s] * rdf(w, i, *flag) * dinv[d];
  }
}

__global__ void k_cvt(const void* src, long off, float* dst, int n, const int* flag){
  int i = blockIdx.x*blockDim.x + threadIdx.x;
  if (i < n) dst[i] = rdf(src, off + i, *flag);
}
__global__ void k_zero(float* p, int n){
  int i = blockIdx.x*blockDim.x + threadIdx.x;
  if (i < n) p[i] = 0.f;
}

// ---------------- weight swizzle into MFMA B-fragment order ----------------
// b-frag for (ks, ct): lane l, elem j <- B[ks*32 + 8*(l>>4)+j][ct*16 + (l&15)]
// stored at dst[((ks*NCT + ct)*64 + l)*8 + j]
// mode 0: B = src1 [K,N] row-major (flag dtype)
// mode 1: GRU cat: K=256, N=512; src1=Wih[384,128], src2=Whh[384,128]
__global__ void k_swz(const void* s1, const void* s2, ushort* dst,
                      int K, int N, int mode, const int* flag){
  int total = (K/32)*(N/16)*512;
  int o = blockIdx.x*blockDim.x + threadIdx.x;
  if (o >= total) return;
  int nct = N/16;
  int ks = o / (nct*512);
  int r1 = o % (nct*512);
  int ct = r1 / 512;
  int r2 = r1 % 512;
  int l  = r2 >> 3;
  int j  = r2 & 7;
  int k  = ks*32 + ((l>>4)<<3) + j;
  int c  = ct*16 + (l&15);
  float v;
  int isbf = *flag;
  if (mode == 0){
    v = rdf(s1, (long)k*N + c, isbf);
  } else {
    if (k < HH){
      if (c < 3*HH) v = rdf(s1, (long)c*HH + k, isbf);               // r,z,i_n from Wih
      else          v = 0.f;                                          // h_n x-part
    } else {
      int kh = k - HH;
      if (c < 2*HH)      v = rdf(s2, (long)c*HH + kh, isbf);         // r,z from Whh
      else if (c < 3*HH) v = 0.f;                                     // i_n h-part
      else               v = rdf(s2, (long)(c-HH)*HH + kh, isbf);    // h_n from Whh
    }
  }
  dst[o] = f2bu(v);
}

// bias4[c]: c<256: bih[c]+bhh[c]; c<384: bih[c]; else bhh[c-128]
__global__ void k_bias4(const void* bih, const void* bhh, float* bias4, const int* flag){
  int c = blockIdx.x*blockDim.x + threadIdx.x;
  if (c >= 4*HH) return;
  int isbf = *flag;
  float v;
  if (c < 2*HH)      v = rdf(bih, c, isbf) + rdf(bhh, c, isbf);
  else if (c < 3*HH) v = rdf(bih, c, isbf);
  else               v = rdf(bhh, c - HH, isbf);
  bias4[c] = v;
}

// ---------------- MFMA GEMM, N=128, BM=64 tile, 4 waves ----------------
// MODE 0: A = x_seq (flag dtype, offset aoff), +bias +relu        (G1, K=64)
// MODE 1: A = bf16 plain                                          (G2, K=128)
// MODE 2: A = bf16 agg, affine(scale,shift)+relu at load          (G3, K=128)
template<int MODE, int K>
__global__ __launch_bounds__(256) void k_mgemm(const void* A, long aoff, const int* flag,
    const float* bias, const float* scale, const float* shift,
    const short8* Bsw, ushort* out)
{
  __shared__ __align__(16) ushort As[64*(K+8)];
  const int tid = threadIdx.x;
  const int bm  = blockIdx.x * 64;
  {
    const int KQ = K/4;                 // elems per thread (16 or 32)
    int row = tid >> 2, kq = tid & 3;
    int grow = bm + row;
    short8* d = (short8*)&As[row*(K+8) + kq*KQ];
    if (MODE == 0){
      if (grow < NN){
        if (*flag){
          const short8* s = (const short8*)((const ushort*)A + aoff + (long)grow*K + kq*KQ);
          #pragma unroll
          for (int i=0;i<KQ/8;i++) d[i] = s[i];
        } else {
          const f32x4* s = (const f32x4*)((const float*)A + aoff + (long)grow*K + kq*KQ);
          #pragma unroll
          for (int i=0;i<KQ/8;i++){
            f32x4 f0 = s[2*i], f1 = s[2*i+1];
            V8 r;
            #pragma unroll
            for (int j=0;j<4;j++){ r.u[j] = f2bu(f0[j]); r.u[4+j] = f2bu(f1[j]); }
            d[i] = r.v;
          }
        }
      } else {
        V8 z; 
        #pragma unroll
        for (int j=0;j<8;j++) z.u[j]=0;
        #pragma unroll
        for (int i=0;i<KQ/8;i++) d[i] = z.v;
      }
    } else if (MODE == 1){
      const short8* s = (const short8*)((const ushort*)A + (long)grow*K + kq*KQ);
      #pragma unroll
      for (int i=0;i<KQ/8;i++) d[i] = s[i];
    } else {
      const short8* s = (const short8*)((const ushort*)A + (long)grow*K + kq*KQ);
      #pragma unroll
      for (int i=0;i<KQ/8;i++){
        V8 a; a.v = s[i]; V8 r;
        #pragma unroll
        for (int j=0;j<8;j++){
          int k = kq*KQ + i*8 + j;
          float v = bu2f(a.u[j])*scale[k] + shift[k];
          r.u[j] = f2bu(fmaxf(v, 0.f));
        }
        d[i] = r.v;
      }
    }
  }
  __syncthreads();
  const int w = tid >> 6, l = tid & 63;
  f32x4 acc[4][2];
  #pragma unroll
  for (int i=0;i<4;i++)
    #pragma unroll
    for (int j=0;j<2;j++) acc[i][j] = (f32x4){0.f,0.f,0.f,0.f};
  #pragma unroll
  for (int ks=0; ks<K/32; ks++){
    short8 a[4], b[2];
    #pragma unroll
    for (int rt=0;rt<4;rt++)
      a[rt] = *reinterpret_cast<const short8*>(&As[(rt*16 + (l&15))*(K+8) + ks*32 + ((l>>4)<<3)]);
    #pragma unroll
    for (int c2=0;c2<2;c2++)
      b[c2] = Bsw[(ks*8 + (w*2+c2))*64 + l];
    #pragma unroll
    for (int rt=0;rt<4;rt++)
      #pragma unroll
      for (int c2=0;c2<2;c2++)
        acc[rt][c2] = __builtin_amdgcn_mfma_f32_16x16x32_bf16(a[rt], b[c2], acc[rt][c2], 0,0,0);
  }
  #pragma unroll
  for (int rt=0;rt<4;rt++)
    #pragma unroll
    for (int c2=0;c2<2;c2++){
      int col = w*32 + c2*16 + (l&15);
      #pragma unroll
      for (int reg=0;reg<4;reg++){
        int grow = bm + rt*16 + ((l>>4)<<2) + reg;
        float v = acc[rt][c2][reg];
        if (MODE==0) v = fmaxf(v + bias[col], 0.f);
        out[(long)grow*HH + col] = f2bu(v);
      }
    }
}

// ---------------- fused GRU step: [x|h]@[256,512] -> gates -> h ----------------
// XMODE 0: x = bf16 agg + affine+relu (GRU layer 0)
// XMODE 1: x = fp32 plain (GRU layer 1, x = h0)
template<int XMODE>
__global__ __launch_bounds__(256) void k_mgru(const void* xsrc, const float* hprev,
    const float* scale, const float* shift,
    const short8* Bsw, const float* bias4, float* hout)
{
  __shared__ __align__(16) ushort As[64*264];
  const int tid = threadIdx.x;
  const int bm = blockIdx.x*64;
  {
    int row = tid>>2, kq = tid&3;       // each thread: 64 elems
    int grow = bm + row;
    short8* d = (short8*)&As[row*264 + kq*64];
    if (kq < 2){
      if (XMODE==0){
        const short8* s = (const short8*)((const ushort*)xsrc + (long)grow*HH + kq*64);
        #pragma unroll
        for (int i=0;i<8;i++){
          V8 a; a.v = s[i]; V8 r;
          #pragma unroll
          for (int j=0;j<8;j++){
            int k = kq*64 + i*8 + j;
            float v = bu2f(a.u[j])*scale[k] + shift[k];
            r.u[j] = f2bu(fmaxf(v,0.f));
          }
          d[i] = r.v;
        }
      } else {
        const f32x4* s = (const f32x4*)((const float*)xsrc + (long)grow*HH + kq*64);
        #pragma unroll
        for (int i=0;i<8;i++){
          f32x4 f0 = s[2*i], f1 = s[2*i+1];
          V8 r;
          #pragma unroll
          for (int j=0;j<4;j++){ r.u[j] = f2bu(f0[j]); r.u[4+j] = f2bu(f1[j]); }
          d[i] = r.v;
        }
      }
    } else {
      const f32x4* s = (const f32x4*)(hprev + (long)grow*HH + (kq-2)*64);
      #pragma unroll
      for (int i=0;i<8;i++){
        f32x4 f0 = s[2*i], f1 = s[2*i+1];
        V8 r;
        #pragma unroll
        for (int j=0;j<4;j++){ r.u[j] = f2bu(f0[j]); r.u[4+j] = f2bu(f1[j]); }
        d[i] = r.v;
      }
    }
  }
  __syncthreads();
  const int w = tid>>6, l = tid&63;
  f32x4 acc[4][4][2];   // [row-tile][gate][col-half]
  #pragma unroll
  for (int i=0;i<4;i++)
    #pragma unroll
    for (int g=0;g<4;g++)
      #pragma unroll
      for (int j=0;j<2;j++) acc[i][g][j] = (f32x4){0.f,0.f,0.f,0.f};
  for (int ks=0; ks<8; ks++){
    short8 a[4];
    #pragma unroll
    for (int rt=0;rt<4;rt++)
      a[rt] = *reinterpret_cast<const short8*>(&As[(rt*16 + (l&15))*264 + ks*32 + ((l>>4)<<3)]);
    #pragma unroll
    for (int g=0;g<4;g++){
      short8 b[2];
      #pragma unroll
      for (int c2=0;c2<2;c2++)
        b[c2] = Bsw[(ks*32 + (g*8 + w*2 + c2))*64 + l];
      #pragma unroll
      for (int rt=0;rt<4;rt++)
        #pragma unroll
        for (int c2=0;c2<2;c2++)
          acc[rt][g][c2] = __builtin_amdgcn_mfma_f32_16x16x32_bf16(a[rt], b[c2], acc[rt][g][c2], 0,0,0);
    }
  }
  // epilogue: gates -> hnew
  #pragma unroll
  for (int rt=0;rt<4;rt++)
    #pragma unroll
    for (int c2=0;c2<2;c2++){
      int col = w*32 + c2*16 + (l&15);
      float br = bias4[col], bz = bias4[HH+col], bi = bias4[2*HH+col], bh = bias4[3*HH+col];
      #pragma unroll
      for (int reg=0;reg<4;reg++){
        int grow = bm + rt*16 + ((l>>4)<<2) + reg;
        float rp = acc[rt][0][c2][reg] + br;
        float zp = acc[rt][1][c2][reg] + bz;
        float ip = acc[rt][2][c2][reg] + bi;
        float hp = acc[rt][3][c2][reg] + bh;
        float r = 1.f/(1.f + expf(-rp));
        float z = 1.f/(1.f + expf(-zp));
        float nc = tanhf(ip + r*hp);
        float hv = hprev[(long)grow*HH + col];
        hout[(long)grow*HH + col] = (1.f - z)*nc + z*hv;
      }
    }
}

// ---------------- conv (CSR gather), max TLP: one node per block ----------------
__global__ __launch_bounds__(128) void k_conv(const ushort* in, ushort* out,
    const int* offs, const int* csr_src, const float* csr_norm, const float* selfn)
{
  int n = blockIdx.x;
  int h = threadIdx.x;
  float acc = selfn[n] * bu2f(in[(long)n*HH + h]);
  int e0 = offs[n], e1 = offs[n+1];
  int e = e0;
  for (; e + 1 < e1; e += 2){
    int   s0 = csr_src[e],   s1 = csr_src[e+1];
    float w0 = csr_norm[e],  w1 = csr_norm[e+1];
    float v0 = bu2f(in[(long)s0*HH + h]);
    float v1 = bu2f(in[(long)s1*HH + h]);
    acc += w0*v0 + w1*v1;
  }
  if (e < e1)
    acc += csr_norm[e] * bu2f(in[(long)csr_src[e]*HH + h]);
  out[(long)n*HH + h] = f2bu(acc);
}

// ---------------- BN stats over bf16 buffer: sums[0:H]=sum, sums[H:2H]=sumsq
__global__ __launch_bounds__(256) void k_bnstats(const ushort* x, float* sums){
  int h = threadIdx.x & 127;
  int g = threadIdx.x >> 7;
  float s = 0.f, ss = 0.f;
  for (int r = blockIdx.x*2 + g; r < NN; r += gridDim.x*2){
    float v = bu2f(x[(long)r*HH + h]);
    s += v; ss += v*v;
  }
  __shared__ float sh[2][HH], shq[2][HH];
  sh[g][h] = s; shq[g][h] = ss;
  __syncthreads();
  if (g == 0){
    atomicAdd(&sums[h],    sh[0][h] + sh[1][h]);
    atomicAdd(&sums[HH+h], shq[0][h] + shq[1][h]);
  }
}

// ---------------- BN finalize: sums -> scale/shift; re-zero sums ----------------
__global__ void k_fin(float* sums, const void* g, const void* be,
                      float* scale, float* shift, const int* flag){
  int h = threadIdx.x;
  if (h >= HH) return;
  float inv_n = 1.0f/(float)NN;
  float mu  = sums[h]*inv_n;
  float var = fmaxf(sums[HH+h]*inv_n - mu*mu, 0.f);
  float sc  = rdf(g, h, *flag) * rsqrtf(var + BN_EPS);
  scale[h] = sc;
  shift[h] = rdf(be, h, *flag) - mu*sc;
  sums[h] = 0.f; sums[HH+h] = 0.f;
}

// ---------------- output head ----------------
__global__ void k_out(const float* h, const float* Wo, const float* bo, void* out, int n,
                      const int* flag){
  __shared__ float Ws[HH][CC+1];
  __shared__ float bs[CC];
  int tid = threadIdx.x;
  for (int i = tid; i < HH*CC; i += 256) Ws[i/CC][i%CC] = Wo[i];
  if (tid < CC) bs[tid] = bo[tid];
  __syncthreads();
  int row = blockIdx.x*16 + (tid >> 4);
  int c   = tid & 15;
  if (row >= n) return;
  const float* hr = h + (size_t)row*HH;
  float s = bs[c];
  #pragma unroll 8
  for (int j = 0; j < HH; j++) s += hr[j]*Ws[j][c];
  float m = s;
  for (int o = 8; o; o >>= 1) m = fmaxf(m, __shfl_xor(m, o, 16));
  float e = expf(s - m);
  float sum = e;
  for (int o = 8; o; o >>= 1) sum += __shfl_xor(sum, o, 16);
  float v = s - m - logf(sum);
  size_t idx = (size_t)row*CC + c;
  if (*flag) ((bf16*)out)[idx] = __float2bfloat16(v);
  else       ((float*)out)[idx] = v;
}

// ---------------- launcher ----------------
static inline size_t alignup(size_t x){ return (x + 255) & ~(size_t)255; }
static inline int ceil_div(int a, int b){ return (a + b - 1)/b; }

extern "C" void kernel_launch(void* const* d_in, const int* in_sizes, int n_in,
                              void* d_out, int out_size, void* d_ws, size_t ws_size,
                              hipStream_t stream){
  const void* x_seq = d_in[0];
  const int*  eidx  = (const int*)d_in[1];
  const void* ew    = d_in[2];
  const void* W_in  = d_in[3];
  const void* b_in  = d_in[4];
  const void* W1    = d_in[5];
  // d_in[6] = bc1 : cancels under training-mode BN
  const void* g1    = d_in[7];
  const void* be1   = d_in[8];
  const void* W2    = d_in[9];
  // d_in[10] = bc2 : cancels under BN
  const void* g2    = d_in[11];
  const void* be2   = d_in[12];
  const void* Wih0  = d_in[13];
  const void* Whh0  = d_in[14];
  const void* bih0  = d_in[15];
  const void* bhh0  = d_in[16];
  const void* Wih1  = d_in[17];
  const void* Whh1  = d_in[18];
  const void* bih1  = d_in[19];
  const void* bhh1  = d_in[20];
  const void* W_out = d_in[21];
  const void* b_out = d_in[22];
  const int* src = eidx;
  const int* dst = eidx + EE;

  // workspace (~48 MB)
  char* p = (char*)d_ws;
  auto alloc = [&](size_t bytes)->void*{ void* r = (void*)p; p += alignup(bytes); return r; };
  int*   flag     = (int*)  alloc(4);
  float* deg      = (float*)alloc(NN*4);
  float* dinv     = (float*)alloc(NN*4);
  float* selfn    = (float*)alloc(NN*4);
  int*   cnt      = (int*)  alloc(NN*4);
  int*   cursor   = (int*)  alloc(NN*4);
  int*   offs     = (int*)  alloc((NN+1)*4);
  int*   csr_src  = (int*)  alloc((size_t)EE*4);
  float* csr_norm = (float*)alloc((size_t)EE*4);
  ushort* B1sw  = (ushort*)alloc((size_t)(FF/32)*(HH/16)*512*2);      // 16 KB
  ushort* B2sw  = (ushort*)alloc((size_t)(HH/32)*(HH/16)*512*2);      // 32 KB
  ushort* B3sw  = (ushort*)alloc((size_t)(HH/32)*(HH/16)*512*2);
  ushort* BG0sw = (ushort*)alloc((size_t)8*32*512*2);                 // 256 KB
  ushort* BG1sw = (ushort*)alloc((size_t)8*32*512*2);
  float* bias4_0 = (float*)alloc(4*HH*4);
  float* bias4_1 = (float*)alloc(4*HH*4);
  float* b_inF   = (float*)alloc(HH*4);
  float* W_outF  = (float*)alloc(HH*CC*4);
  float* b_outF  = (float*)alloc(CC*4);
  float* scale1  = (float*)alloc(HH*4);
  float* shift1  = (float*)alloc(HH*4);
  float* scale2  = (float*)alloc(HH*4);
  float* shift2  = (float*)alloc(HH*4);
  float* sums    = (float*)alloc(2*HH*4);
  ushort* temp1b = (ushort*)alloc((size_t)M_PAD*HH*2);  // 5.13 MB
  ushort* temp2b = (ushort*)alloc((size_t)M_PAD*HH*2);
  ushort* agg1b  = (ushort*)alloc((size_t)M_PAD*HH*2);
  ushort* agg2b  = (ushort*)alloc((size_t)M_PAD*HH*2);
  float*  h0buf  = (float*)alloc((size_t)M_PAD*HH*4);   // 10.26 MB
  float*  h1buf  = (float*)alloc((size_t)M_PAD*HH*4);
  (void)ws_size; (void)n_in; (void)in_sizes; (void)out_size;

  const int TPB = 256;
  // ---- dtype probe + graph setup ----
  k_detect<<<1, 256, 0, stream>>>(x_seq, flag);
  k_init<<<ceil_div(NN,TPB), TPB, 0, stream>>>(deg, cnt, cursor, NN);
  k_deg <<<ceil_div(EE,TPB), TPB, 0, stream>>>(src, dst, ew, deg, cnt, EE, flag);
  k_dinv<<<ceil_div(NN,TPB), TPB, 0, stream>>>(deg, dinv, selfn, NN);
  k_scan<<<1, 256, 0, stream>>>(cnt, offs, NN);
  k_fill<<<ceil_div(EE,TPB), TPB, 0, stream>>>(src, dst, ew, dinv, offs, cursor, csr_src, csr_norm, EE, flag);

  // ---- weight prep ----
  k_swz<<<ceil_div(2*8*512,TPB), TPB, 0, stream>>>(W_in, nullptr, B1sw, FF, HH, 0, flag);
  k_swz<<<ceil_div(4*8*512,TPB), TPB, 0, stream>>>(W1,   nullptr, B2sw, HH, HH, 0, flag);
  k_swz<<<ceil_div(4*8*512,TPB), TPB, 0, stream>>>(W2,   nullptr, B3sw, HH, HH, 0, flag);
  k_swz<<<ceil_div(8*32*512,TPB), TPB, 0, stream>>>(Wih0, Whh0, BG0sw, 2*HH, 4*HH, 1, flag);
  k_swz<<<ceil_div(8*32*512,TPB), TPB, 0, stream>>>(Wih1, Whh1, BG1sw, 2*HH, 4*HH, 1, flag);
  k_bias4<<<2, 256, 0, stream>>>(bih0, bhh0, bias4_0, flag);
  k_bias4<<<2, 256, 0, stream>>>(bih1, bhh1, bias4_1, flag);
  k_cvt<<<1, 128, 0, stream>>>(b_in, 0, b_inF, HH, flag);
  k_cvt<<<ceil_div(HH*CC,TPB), TPB, 0, stream>>>(W_out, 0, W_outF, HH*CC, flag);
  k_cvt<<<1, CC, 0, stream>>>(b_out, 0, b_outF, CC, flag);
  int totH = M_PAD*HH;
  k_zero<<<ceil_div(totH,TPB), TPB, 0, stream>>>(h0buf, totH);
  k_zero<<<ceil_div(totH,TPB), TPB, 0, stream>>>(h1buf, totH);
  k_zero<<<1, 256, 0, stream>>>(sums, 2*HH);

  // ---- main temporal loop ----
  for (int t = 0; t < T_STEPS; t++){
    long aoff = (long)t*NN*FF;
    k_mgemm<0,FF><<<NBLK, 256, 0, stream>>>(x_seq, aoff, flag, b_inF, nullptr, nullptr,
                                            (const short8*)B1sw, temp1b);
    k_mgemm<1,HH><<<NBLK, 256, 0, stream>>>(temp1b, 0, flag, nullptr, nullptr, nullptr,
                                            (const short8*)B2sw, temp2b);
    k_conv<<<NN, 128, 0, stream>>>(temp2b, agg1b, offs, csr_src, csr_norm, selfn);
    k_bnstats<<<128, 256, 0, stream>>>(agg1b, sums);
    k_fin<<<1, 128, 0, stream>>>(sums, g1, be1, scale1, shift1, flag);
    k_mgemm<2,HH><<<NBLK, 256, 0, stream>>>(agg1b, 0, flag, nullptr, scale1, shift1,
                                            (const short8*)B3sw, temp2b);
    k_conv<<<NN, 128, 0, stream>>>(temp2b, agg2b, offs, csr_src, csr_norm, selfn);
    k_bnstats<<<128, 256, 0, stream>>>(agg2b, sums);
    k_fin<<<1, 128, 0, stream>>>(sums, g2, be2, scale2, shift2, flag);
    k_mgru<0><<<NBLK, 256, 0, stream>>>(agg2b, h0buf, scale2, shift2,
                                        (const short8*)BG0sw, bias4_0, h0buf);
    k_mgru<1><<<NBLK, 256, 0, stream>>>(h0buf, h1buf, nullptr, nullptr,
                                        (const short8*)BG1sw, bias4_1, h1buf);
  }

  // ---- output head ----
  k_out<<<ceil_div(NN,16), 256, 0, stream>>>(h1buf, W_outF, b_outF, d_out, NN, flag);
}

// Round 6
// 3570.101 us; speedup vs baseline: 4.1950x; 1.0337x over previous
//
#include <hip/hip_runtime.h>
#include <hip/hip_bf16.h>
#include <stdint.h>

#define T_STEPS 16
#define NN      20000
#define M_PAD   20032     // 626 * 32
#define NB32    626
#define EE      640000
#define FF      64
#define HH      128
#define CC      16
#define BN_EPS  1e-5f
#define INVN    (1.0f/(float)NN)

typedef __hip_bfloat16 bf16;
typedef __attribute__((ext_vector_type(8))) short short8;
typedef __attribute__((ext_vector_type(4))) float f32x4;

union V8 { short8 v; ushort u[8]; };

__device__ __forceinline__ float rdf(const void* p, long i, int isbf){
  return isbf ? __bfloat162float(((const bf16*)p)[i]) : ((const float*)p)[i];
}
__device__ __forceinline__ ushort f2bu(float f){
  bf16 h = __float2bfloat16(f);
  return *reinterpret_cast<ushort*>(&h);
}
__device__ __forceinline__ float bu2f(ushort u){
  bf16 h; *reinterpret_cast<ushort*>(&h) = u;
  return __bfloat162float(h);
}

// ---------------- dtype probe (flag=1 iff buffers are bf16) ----------------
__global__ void k_detect(const void* x, int* flag){
  __shared__ int sh[256];
  int tid = threadIdx.x;
  const uint16_t* u = (const uint16_t*)x;
  uint16_t v = u[2*tid];
  int e = (v >> 7) & 0xFF;
  sh[tid] = (e >= 120 && e <= 134) ? 1 : 0;
  __syncthreads();
  for (int o = 128; o; o >>= 1){ if (tid < o) sh[tid] += sh[tid+o]; __syncthreads(); }
  if (tid == 0) flag[0] = (sh[0] >= 128) ? 1 : 0;
}

// ---------------- graph setup ----------------
__global__ void k_init(float* deg, int* cnt, int* cursor, int n){
  int i = blockIdx.x*blockDim.x + threadIdx.x;
  if (i < n){ deg[i] = 1.0f; cnt[i] = 0; cursor[i] = 0; }
}
__global__ void k_deg(const int* src, const int* dst, const void* w,
                      float* deg, int* cnt, int e, const int* flag){
  int i = blockIdx.x*blockDim.x + threadIdx.x;
  if (i < e){
    int d = dst[i];
    atomicAdd(&deg[d], rdf(w, i, *flag));
    atomicAdd(&cnt[d], 1);
  }
}
__global__ void k_dinv(const float* deg, float* dinv, float* selfnorm, int n){
  int i = blockIdx.x*blockDim.x + threadIdx.x;
  if (i < n){
    float d = deg[i];
    float r = d > 0.f ? rsqrtf(d) : 0.f;
    dinv[i] = r; selfnorm[i] = r*r;
  }
}
__global__ void k_scan(const int* cnt, int* offs, int n){
  __shared__ int part[256];
  int tid = threadIdx.x;
  int chunk = (n + 255)/256;
  int lo = tid*chunk; int hi = lo + chunk;
  if (hi > n) hi = n;
  if (lo > n) lo = n;
  int s = 0;
  for (int i = lo; i < hi; i++) s += cnt[i];
  part[tid] = s;
  __syncthreads();
  for (int off = 1; off < 256; off <<= 1){
    int t = (tid >= off) ? part[tid-off] : 0;
    __syncthreads();
    part[tid] += t;
    __syncthreads();
  }
  int run = part[tid] - s;
  for (int i = lo; i < hi; i++){ offs[i] = run; run += cnt[i]; }
  if (tid == 255) offs[n] = part[255];
}
__global__ void k_fill(const int* src, const int* dst, const void* w, const float* dinv,
                       const int* offs, int* cursor, int* csr_src, float* csr_norm, int e,
                       const int* flag){
  int i = blockIdx.x*blockDim.x + threadIdx.x;
  if (i < e){
    int s = src[i], d = dst[i];
    int pos = offs[d] + atomicAdd(&cursor[d], 1);
    csr_src[pos]  = s;
    csr_norm[pos] = dinv[s] * rdf(w, i, *flag) * dinv[d];
  }
}

__global__ void k_cvt(const void* src, long off, float* dst, int n, const int* flag){
  int i = blockIdx.x*blockDim.x + threadIdx.x;
  if (i < n) dst[i] = rdf(src, off + i, *flag);
}
__global__ void k_zero(float* p, int n){
  int i = blockIdx.x*blockDim.x + threadIdx.x;
  if (i < n) p[i] = 0.f;
}

// ---------------- weight swizzle into MFMA B-fragment order ----------------
// b-frag (ks, ct): lane l, elem j <- B[ks*32 + 8*(l>>4)+j][ct*16 + (l&15)]
// stored at dst[((ks*NCT + ct)*64 + l)*8 + j]
// mode 0: B = src1 [K,N] row-major. mode 1: GRU cat K=256,N=512 from Wih/Whh [384,128].
__global__ void k_swz(const void* s1, const void* s2, ushort* dst,
                      int K, int N, int mode, const int* flag){
  int total = (K/32)*(N/16)*512;
  int o = blockIdx.x*blockDim.x + threadIdx.x;
  if (o >= total) return;
  int nct = N/16;
  int ks = o / (nct*512);
  int r1 = o % (nct*512);
  int ct = r1 / 512;
  int r2 = r1 % 512;
  int l  = r2 >> 3;
  int j  = r2 & 7;
  int k  = ks*32 + ((l>>4)<<3) + j;
  int c  = ct*16 + (l&15);
  float v;
  int isbf = *flag;
  if (mode == 0){
    v = rdf(s1, (long)k*N + c, isbf);
  } else {
    if (k < HH){
      if (c < 3*HH) v = rdf(s1, (long)c*HH + k, isbf);               // r,z,i_n from Wih
      else          v = 0.f;                                          // h_n x-part
    } else {
      int kh = k - HH;
      if (c < 2*HH)      v = rdf(s2, (long)c*HH + kh, isbf);         // r,z from Whh
      else if (c < 3*HH) v = 0.f;                                     // i_n h-part
      else               v = rdf(s2, (long)(c-HH)*HH + kh, isbf);    // h_n from Whh
    }
  }
  dst[o] = f2bu(v);
}

// bias4[c]: c<256: bih[c]+bhh[c]; c<384: bih[c]; else bhh[c-128]
__global__ void k_bias4(const void* bih, const void* bhh, float* bias4, const int* flag){
  int c = blockIdx.x*blockDim.x + threadIdx.x;
  if (c >= 4*HH) return;
  int isbf = *flag;
  float v;
  if (c < 2*HH)      v = rdf(bih, c, isbf) + rdf(bhh, c, isbf);
  else if (c < 3*HH) v = rdf(bih, c, isbf);
  else               v = rdf(bhh, c - HH, isbf);
  bias4[c] = v;
}

// ---------------- MFMA GEMM, N=128, BM=32 tile, 4 waves, grid NB32 ----------------
// MODE 0: A = x_seq (flag dtype, offset aoff), +bias +relu        (G1, K=64)
// MODE 1: A = bf16 plain                                          (G2, K=128)
// MODE 2: A = bf16 agg, inline-BN(sums,gw,bew)+relu at load       (G3, K=128)
template<int MODE, int K>
__global__ __launch_bounds__(256) void k_mgemm(const void* A, long aoff, const int* flag,
    const float* bias, const float* sums, const void* gw, const void* bew,
    const short8* Bsw, ushort* out)
{
  __shared__ __align__(16) ushort As[32*K];
  const int tid = threadIdx.x;
  const int bm  = blockIdx.x * 32;
  {
    const int CH = K/64;                  // short8 chunks per thread
    int row = tid >> 3, seg = tid & 7;
    int grow = bm + row;
    int isbf = *flag;
    #pragma unroll
    for (int i=0;i<CH;i++){
      int colu = seg*(K/8) + i*8;
      int idx  = row*K + (colu ^ ((row&7)<<3));
      V8 r;
      if (MODE == 0){
        if (grow < NN){
          if (isbf){
            r.v = *(const short8*)((const ushort*)A + aoff + (long)grow*K + colu);
          } else {
            const f32x4* s = (const f32x4*)((const float*)A + aoff + (long)grow*K + colu);
            f32x4 f0 = s[0], f1 = s[1];
            #pragma unroll
            for (int j=0;j<4;j++){ r.u[j] = f2bu(f0[j]); r.u[4+j] = f2bu(f1[j]); }
          }
        } else {
          #pragma unroll
          for (int j=0;j<8;j++) r.u[j] = 0;
        }
      } else if (MODE == 1){
        r.v = *(const short8*)((const ushort*)A + (long)grow*K + colu);
      } else {
        V8 a; a.v = *(const short8*)((const ushort*)A + (long)grow*K + colu);
        #pragma unroll
        for (int j=0;j<8;j++){
          int k = colu + j;
          float mu  = sums[k]*INVN;
          float var = fmaxf(sums[HH+k]*INVN - mu*mu, 0.f);
          float sc  = rdf(gw, k, isbf) * rsqrtf(var + BN_EPS);
          float sh  = rdf(bew, k, isbf) - mu*sc;
          r.u[j] = f2bu(fmaxf(bu2f(a.u[j])*sc + sh, 0.f));
        }
      }
      *(short8*)&As[idx] = r.v;
    }
  }
  __syncthreads();
  const int w = tid >> 6, l = tid & 63;
  f32x4 acc[2][2];
  #pragma unroll
  for (int i=0;i<2;i++)
    #pragma unroll
    for (int j=0;j<2;j++) acc[i][j] = (f32x4){0.f,0.f,0.f,0.f};
  #pragma unroll
  for (int ks=0; ks<K/32; ks++){
    short8 a[2], b[2];
    #pragma unroll
    for (int rt=0;rt<2;rt++){
      int row = rt*16 + (l&15);
      int colu = ks*32 + ((l>>4)<<3);
      a[rt] = *reinterpret_cast<const short8*>(&As[row*K + (colu ^ ((row&7)<<3))]);
    }
    #pragma unroll
    for (int c2=0;c2<2;c2++)
      b[c2] = Bsw[(ks*8 + (w*2+c2))*64 + l];
    #pragma unroll
    for (int rt=0;rt<2;rt++)
      #pragma unroll
      for (int c2=0;c2<2;c2++)
        acc[rt][c2] = __builtin_amdgcn_mfma_f32_16x16x32_bf16(a[rt], b[c2], acc[rt][c2], 0,0,0);
  }
  #pragma unroll
  for (int rt=0;rt<2;rt++)
    #pragma unroll
    for (int c2=0;c2<2;c2++){
      int col = w*32 + c2*16 + (l&15);
      #pragma unroll
      for (int reg=0;reg<4;reg++){
        int grow = bm + rt*16 + ((l>>4)<<2) + reg;
        float v = acc[rt][c2][reg];
        if (MODE==0) v = fmaxf(v + bias[col], 0.f);
        out[(long)grow*HH + col] = f2bu(v);
      }
    }
}

// ---------------- fused GRU step: [x|h]@[256,512] -> gates -> h ----------------
// grid (NB32, 2): 32 rows x 64 h-cols per block. NOT in-place (hout != hprev).
// XMODE 0: x = bf16 agg + inline-BN+relu (GRU layer 0)
// XMODE 1: x = fp32 plain (GRU layer 1, x = h0_new)
template<int XMODE>
__global__ __launch_bounds__(256) void k_mgru(const void* xsrc, const float* hprev,
    const int* flag, const float* sums, const void* gw, const void* bew,
    const short8* Bsw, const float* bias4, float* hout)
{
  __shared__ __align__(16) ushort As[32*256];
  const int tid = threadIdx.x;
  const int bm = blockIdx.x*32;
  const int cb = blockIdx.y;            // column block: h-cols [cb*64, cb*64+64)
  {
    int row = tid>>3, seg = tid&7;
    int grow = bm + row;
    int isbf = *flag;
    #pragma unroll
    for (int i=0;i<4;i++){
      V8 r;
      int colu;
      if (seg < 4){
        int c0 = seg*32 + i*8;
        colu = c0;
        if (XMODE==0){
          V8 a; a.v = *(const short8*)((const ushort*)xsrc + (long)grow*HH + c0);
          #pragma unroll
          for (int j=0;j<8;j++){
            int k = c0 + j;
            float mu  = sums[k]*INVN;
            float var = fmaxf(sums[HH+k]*INVN - mu*mu, 0.f);
            float sc  = rdf(gw, k, isbf) * rsqrtf(var + BN_EPS);
            float sh  = rdf(bew, k, isbf) - mu*sc;
            r.u[j] = f2bu(fmaxf(bu2f(a.u[j])*sc + sh, 0.f));
          }
        } else {
          const f32x4* s = (const f32x4*)((const float*)xsrc + (long)grow*HH + c0);
          f32x4 f0 = s[0], f1 = s[1];
          #pragma unroll
          for (int j=0;j<4;j++){ r.u[j] = f2bu(f0[j]); r.u[4+j] = f2bu(f1[j]); }
        }
      } else {
        int c0 = (seg-4)*32 + i*8;
        colu = 128 + c0;
        const f32x4* s = (const f32x4*)(hprev + (long)grow*HH + c0);
        f32x4 f0 = s[0], f1 = s[1];
        #pragma unroll
        for (int j=0;j<4;j++){ r.u[j] = f2bu(f0[j]); r.u[4+j] = f2bu(f1[j]); }
      }
      *(short8*)&As[row*256 + (colu ^ ((row&7)<<3))] = r.v;
    }
  }
  __syncthreads();
  const int w = tid>>6, l = tid&63;
  f32x4 acc[2][4];   // [row-tile][gate]
  #pragma unroll
  for (int i=0;i<2;i++)
    #pragma unroll
    for (int gg=0;gg<4;gg++) acc[i][gg] = (f32x4){0.f,0.f,0.f,0.f};
  #pragma unroll
  for (int ks=0; ks<8; ks++){
    short8 a[2];
    #pragma unroll
    for (int rt=0;rt<2;rt++){
      int row = rt*16 + (l&15);
      int colu = ks*32 + ((l>>4)<<3);
      a[rt] = *reinterpret_cast<const short8*>(&As[row*256 + (colu ^ ((row&7)<<3))]);
    }
    #pragma unroll
    for (int gg=0;gg<4;gg++){
      short8 b = Bsw[(ks*32 + gg*8 + cb*4 + w)*64 + l];
      #pragma unroll
      for (int rt=0;rt<2;rt++)
        acc[rt][gg] = __builtin_amdgcn_mfma_f32_16x16x32_bf16(a[rt], b, acc[rt][gg], 0,0,0);
    }
  }
  // epilogue: gates -> hnew
  int col = cb*64 + w*16 + (l&15);
  float br = bias4[col], bz = bias4[HH+col], bi = bias4[2*HH+col], bh = bias4[3*HH+col];
  #pragma unroll
  for (int rt=0;rt<2;rt++)
    #pragma unroll
    for (int reg=0;reg<4;reg++){
      int grow = bm + rt*16 + ((l>>4)<<2) + reg;
      float rp = acc[rt][0][reg] + br;
      float zp = acc[rt][1][reg] + bz;
      float ip = acc[rt][2][reg] + bi;
      float hp = acc[rt][3][reg] + bh;
      float r = 1.f/(1.f + expf(-rp));
      float z = 1.f/(1.f + expf(-zp));
      float nc = tanhf(ip + r*hp);
      float hv = hprev[(long)grow*HH + col];
      hout[(long)grow*HH + col] = (1.f - z)*nc + z*hv;
    }
}

// ---------------- conv (CSR gather), max TLP: one node per block ----------------
__global__ __launch_bounds__(128) void k_conv(const ushort* in, ushort* out,
    const int* offs, const int* csr_src, const float* csr_norm, const float* selfn)
{
  int n = blockIdx.x;
  int h = threadIdx.x;
  float acc = selfn[n] * bu2f(in[(long)n*HH + h]);
  int e0 = offs[n], e1 = offs[n+1];
  int e = e0;
  for (; e + 1 < e1; e += 2){
    int   s0 = csr_src[e],   s1 = csr_src[e+1];
    float w0 = csr_norm[e],  w1 = csr_norm[e+1];
    float v0 = bu2f(in[(long)s0*HH + h]);
    float v1 = bu2f(in[(long)s1*HH + h]);
    acc += w0*v0 + w1*v1;
  }
  if (e < e1)
    acc += csr_norm[e] * bu2f(in[(long)csr_src[e]*HH + h]);
  out[(long)n*HH + h] = f2bu(acc);
}

// ---------------- BN stats into per-(t,layer) slot: slot[0:H]=sum, slot[H:2H]=sumsq
__global__ __launch_bounds__(256) void k_bnstats(const ushort* x, float* slot){
  int h = threadIdx.x & 127;
  int g = threadIdx.x >> 7;
  float s = 0.f, ss = 0.f;
  for (int r = blockIdx.x*2 + g; r < NN; r += gridDim.x*2){
    float v = bu2f(x[(long)r*HH + h]);
    s += v; ss += v*v;
  }
  __shared__ float sh[2][HH], shq[2][HH];
  sh[g][h] = s; shq[g][h] = ss;
  __syncthreads();
  if (g == 0){
    atomicAdd(&slot[h],    sh[0][h] + sh[1][h]);
    atomicAdd(&slot[HH+h], shq[0][h] + shq[1][h]);
  }
}

// ---------------- output head ----------------
__global__ void k_out(const float* h, const float* Wo, const float* bo, void* out, int n,
                      const int* flag){
  __shared__ float Ws[HH][CC+1];
  __shared__ float bs[CC];
  int tid = threadIdx.x;
  for (int i = tid; i < HH*CC; i += 256) Ws[i/CC][i%CC] = Wo[i];
  if (tid < CC) bs[tid] = bo[tid];
  __syncthreads();
  int row = blockIdx.x*16 + (tid >> 4);
  int c   = tid & 15;
  if (row >= n) return;
  const float* hr = h + (size_t)row*HH;
  float s = bs[c];
  #pragma unroll 8
  for (int j = 0; j < HH; j++) s += hr[j]*Ws[j][c];
  float m = s;
  for (int o = 8; o; o >>= 1) m = fmaxf(m, __shfl_xor(m, o, 16));
  float e = expf(s - m);
  float sum = e;
  for (int o = 8; o; o >>= 1) sum += __shfl_xor(sum, o, 16);
  float v = s - m - logf(sum);
  size_t idx = (size_t)row*CC + c;
  if (*flag) ((bf16*)out)[idx] = __float2bfloat16(v);
  else       ((float*)out)[idx] = v;
}

// ---------------- launcher ----------------
static inline size_t alignup(size_t x){ return (x + 255) & ~(size_t)255; }
static inline int ceil_div(int a, int b){ return (a + b - 1)/b; }

extern "C" void kernel_launch(void* const* d_in, const int* in_sizes, int n_in,
                              void* d_out, int out_size, void* d_ws, size_t ws_size,
                              hipStream_t stream){
  const void* x_seq = d_in[0];
  const int*  eidx  = (const int*)d_in[1];
  const void* ew    = d_in[2];
  const void* W_in  = d_in[3];
  const void* b_in  = d_in[4];
  const void* W1    = d_in[5];
  // d_in[6] = bc1 : cancels under training-mode BN
  const void* g1    = d_in[7];
  const void* be1   = d_in[8];
  const void* W2    = d_in[9];
  // d_in[10] = bc2 : cancels under BN
  const void* g2    = d_in[11];
  const void* be2   = d_in[12];
  const void* Wih0  = d_in[13];
  const void* Whh0  = d_in[14];
  const void* bih0  = d_in[15];
  const void* bhh0  = d_in[16];
  const void* Wih1  = d_in[17];
  const void* Whh1  = d_in[18];
  const void* bih1  = d_in[19];
  const void* bhh1  = d_in[20];
  const void* W_out = d_in[21];
  const void* b_out = d_in[22];
  const int* src = eidx;
  const int* dst = eidx + EE;

  // workspace (~70 MB)
  char* p = (char*)d_ws;
  auto alloc = [&](size_t bytes)->void*{ void* r = (void*)p; p += alignup(bytes); return r; };
  int*   flag     = (int*)  alloc(4);
  float* deg      = (float*)alloc(NN*4);
  float* dinv     = (float*)alloc(NN*4);
  float* selfn    = (float*)alloc(NN*4);
  int*   cnt      = (int*)  alloc(NN*4);
  int*   cursor   = (int*)  alloc(NN*4);
  int*   offs     = (int*)  alloc((NN+1)*4);
  int*   csr_src  = (int*)  alloc((size_t)EE*4);
  float* csr_norm = (float*)alloc((size_t)EE*4);
  ushort* B1sw  = (ushort*)alloc((size_t)(FF/32)*(HH/16)*512*2);      // 16 KB
  ushort* B2sw  = (ushort*)alloc((size_t)(HH/32)*(HH/16)*512*2);      // 32 KB
  ushort* B3sw  = (ushort*)alloc((size_t)(HH/32)*(HH/16)*512*2);
  ushort* BG0sw = (ushort*)alloc((size_t)8*32*512*2);                 // 256 KB
  ushort* BG1sw = (ushort*)alloc((size_t)8*32*512*2);
  float* bias4_0 = (float*)alloc(4*HH*4);
  float* bias4_1 = (float*)alloc(4*HH*4);
  float* b_inF   = (float*)alloc(HH*4);
  float* W_outF  = (float*)alloc(HH*CC*4);
  float* b_outF  = (float*)alloc(CC*4);
  float* sums_all= (float*)alloc((size_t)T_STEPS*2*2*HH*4);           // 64 KB: [t][layer][2H]
  ushort* temp1b = (ushort*)alloc((size_t)M_PAD*HH*2);  // 5.13 MB
  ushort* temp2b = (ushort*)alloc((size_t)M_PAD*HH*2);
  ushort* agg1b  = (ushort*)alloc((size_t)M_PAD*HH*2);
  ushort* agg2b  = (ushort*)alloc((size_t)M_PAD*HH*2);
  float*  h0bufA = (float*)alloc((size_t)M_PAD*HH*4);   // 10.26 MB (ping-pong)
  float*  h0bufB = (float*)alloc((size_t)M_PAD*HH*4);
  float*  h1bufA = (float*)alloc((size_t)M_PAD*HH*4);
  float*  h1bufB = (float*)alloc((size_t)M_PAD*HH*4);
  (void)ws_size; (void)n_in; (void)in_sizes; (void)out_size;

  const int TPB = 256;
  // ---- dtype probe + graph setup ----
  k_detect<<<1, 256, 0, stream>>>(x_seq, flag);
  k_init<<<ceil_div(NN,TPB), TPB, 0, stream>>>(deg, cnt, cursor, NN);
  k_deg <<<ceil_div(EE,TPB), TPB, 0, stream>>>(src, dst, ew, deg, cnt, EE, flag);
  k_dinv<<<ceil_div(NN,TPB), TPB, 0, stream>>>(deg, dinv, selfn, NN);
  k_scan<<<1, 256, 0, stream>>>(cnt, offs, NN);
  k_fill<<<ceil_div(EE,TPB), TPB, 0, stream>>>(src, dst, ew, dinv, offs, cursor, csr_src, csr_norm, EE, flag);

  // ---- weight prep ----
  k_swz<<<ceil_div(2*8*512,TPB), TPB, 0, stream>>>(W_in, nullptr, B1sw, FF, HH, 0, flag);
  k_swz<<<ceil_div(4*8*512,TPB), TPB, 0, stream>>>(W1,   nullptr, B2sw, HH, HH, 0, flag);
  k_swz<<<ceil_div(4*8*512,TPB), TPB, 0, stream>>>(W2,   nullptr, B3sw, HH, HH, 0, flag);
  k_swz<<<ceil_div(8*32*512,TPB), TPB, 0, stream>>>(Wih0, Whh0, BG0sw, 2*HH, 4*HH, 1, flag);
  k_swz<<<ceil_div(8*32*512,TPB), TPB, 0, stream>>>(Wih1, Whh1, BG1sw, 2*HH, 4*HH, 1, flag);
  k_bias4<<<2, 256, 0, stream>>>(bih0, bhh0, bias4_0, flag);
  k_bias4<<<2, 256, 0, stream>>>(bih1, bhh1, bias4_1, flag);
  k_cvt<<<1, 128, 0, stream>>>(b_in, 0, b_inF, HH, flag);
  k_cvt<<<ceil_div(HH*CC,TPB), TPB, 0, stream>>>(W_out, 0, W_outF, HH*CC, flag);
  k_cvt<<<1, CC, 0, stream>>>(b_out, 0, b_outF, CC, flag);
  int totH = M_PAD*HH;
  k_zero<<<ceil_div(totH,TPB), TPB, 0, stream>>>(h0bufA, totH);
  k_zero<<<ceil_div(totH,TPB), TPB, 0, stream>>>(h1bufA, totH);
  k_zero<<<ceil_div(T_STEPS*2*2*HH,TPB), TPB, 0, stream>>>(sums_all, T_STEPS*2*2*HH);

  float* h0bufs[2] = {h0bufA, h0bufB};
  float* h1bufs[2] = {h1bufA, h1bufB};
  int cur = 0;

  // ---- main temporal loop ----
  for (int t = 0; t < T_STEPS; t++){
    long aoff = (long)t*NN*FF;
    float* slot1 = sums_all + (size_t)(t*2 + 0)*2*HH;
    float* slot2 = sums_all + (size_t)(t*2 + 1)*2*HH;
    int nxt = cur ^ 1;
    k_mgemm<0,FF><<<NB32, 256, 0, stream>>>(x_seq, aoff, flag, b_inF, nullptr, nullptr, nullptr,
                                            (const short8*)B1sw, temp1b);
    k_mgemm<1,HH><<<NB32, 256, 0, stream>>>(temp1b, 0, flag, nullptr, nullptr, nullptr, nullptr,
                                            (const short8*)B2sw, temp2b);
    k_conv<<<NN, 128, 0, stream>>>(temp2b, agg1b, offs, csr_src, csr_norm, selfn);
    k_bnstats<<<128, 256, 0, stream>>>(agg1b, slot1);
    k_mgemm<2,HH><<<NB32, 256, 0, stream>>>(agg1b, 0, flag, nullptr, slot1, g1, be1,
                                            (const short8*)B3sw, temp2b);
    k_conv<<<NN, 128, 0, stream>>>(temp2b, agg2b, offs, csr_src, csr_norm, selfn);
    k_bnstats<<<128, 256, 0, stream>>>(agg2b, slot2);
    k_mgru<0><<<dim3(NB32,2), 256, 0, stream>>>(agg2b, h0bufs[cur], flag, slot2, g2, be2,
                                                (const short8*)BG0sw, bias4_0, h0bufs[nxt]);
    k_mgru<1><<<dim3(NB32,2), 256, 0, stream>>>(h0bufs[nxt], h1bufs[cur], flag, nullptr, nullptr, nullptr,
                                                (const short8*)BG1sw, bias4_1, h1bufs[nxt]);
    cur = nxt;
  }

  // ---- output head ----
  k_out<<<ceil_div(NN,16), 256, 0, stream>>>(h1bufs[cur], W_outF, b_outF, d_out, NN, flag);
}

// Round 7
// 2097.561 us; speedup vs baseline: 7.1400x; 1.7020x over previous
//
#include <hip/hip_runtime.h>
#include <hip/hip_bf16.h>
#include <stdint.h>

#define T_STEPS 16
#define T_CHUNK 4
#define NCHUNK  4
#define NN      20000
#define M_PAD   20032     // 626 * 32
#define NB32    626
#define EE      640000
#define FF      64
#define HH      128
#define CC      16
#define BN_EPS  1e-5f
#define INVN    (1.0f/(float)NN)

typedef __hip_bfloat16 bf16;
typedef __attribute__((ext_vector_type(8))) short short8;
typedef __attribute__((ext_vector_type(4))) float f32x4;

union V8 { short8 v; ushort u[8]; };

__device__ __forceinline__ float rdf(const void* p, long i, int isbf){
  return isbf ? __bfloat162float(((const bf16*)p)[i]) : ((const float*)p)[i];
}
__device__ __forceinline__ ushort f2bu(float f){
  bf16 h = __float2bfloat16(f);
  return *reinterpret_cast<ushort*>(&h);
}
__device__ __forceinline__ float bu2f(ushort u){
  bf16 h; *reinterpret_cast<ushort*>(&h) = u;
  return __bfloat162float(h);
}

// ---------------- dtype probe (flag=1 iff buffers are bf16) ----------------
__global__ void k_detect(const void* x, int* flag){
  __shared__ int sh[256];
  int tid = threadIdx.x;
  const uint16_t* u = (const uint16_t*)x;
  uint16_t v = u[2*tid];
  int e = (v >> 7) & 0xFF;
  sh[tid] = (e >= 120 && e <= 134) ? 1 : 0;
  __syncthreads();
  for (int o = 128; o; o >>= 1){ if (tid < o) sh[tid] += sh[tid+o]; __syncthreads(); }
  if (tid == 0) flag[0] = (sh[0] >= 128) ? 1 : 0;
}

// ---------------- graph setup ----------------
__global__ void k_init(float* deg, int* cnt, int* cursor, int n){
  int i = blockIdx.x*blockDim.x + threadIdx.x;
  if (i < n){ deg[i] = 1.0f; cnt[i] = 0; cursor[i] = 0; }
}
__global__ void k_deg(const int* src, const int* dst, const void* w,
                      float* deg, int* cnt, int e, const int* flag){
  int i = blockIdx.x*blockDim.x + threadIdx.x;
  if (i < e){
    int d = dst[i];
    atomicAdd(&deg[d], rdf(w, i, *flag));
    atomicAdd(&cnt[d], 1);
  }
}
__global__ void k_dinv(const float* deg, float* dinv, float* selfnorm, int n){
  int i = blockIdx.x*blockDim.x + threadIdx.x;
  if (i < n){
    float d = deg[i];
    float r = d > 0.f ? rsqrtf(d) : 0.f;
    dinv[i] = r; selfnorm[i] = r*r;
  }
}
__global__ void k_scan(const int* cnt, int* offs, int n){
  __shared__ int part[256];
  int tid = threadIdx.x;
  int chunk = (n + 255)/256;
  int lo = tid*chunk; int hi = lo + chunk;
  if (hi > n) hi = n;
  if (lo > n) lo = n;
  int s = 0;
  for (int i = lo; i < hi; i++) s += cnt[i];
  part[tid] = s;
  __syncthreads();
  for (int off = 1; off < 256; off <<= 1){
    int t = (tid >= off) ? part[tid-off] : 0;
    __syncthreads();
    part[tid] += t;
    __syncthreads();
  }
  int run = part[tid] - s;
  for (int i = lo; i < hi; i++){ offs[i] = run; run += cnt[i]; }
  if (tid == 255) offs[n] = part[255];
}
__global__ void k_fill(const int* src, const int* dst, const void* w, const float* dinv,
                       const int* offs, int* cursor, int* csr_src, float* csr_norm, int e,
                       const int* flag){
  int i = blockIdx.x*blockDim.x + threadIdx.x;
  if (i < e){
    int s = src[i], d = dst[i];
    int pos = offs[d] + atomicAdd(&cursor[d], 1);
    csr_src[pos]  = s;
    csr_norm[pos] = dinv[s] * rdf(w, i, *flag) * dinv[d];
  }
}

__global__ void k_cvt(const void* src, long off, float* dst, int n, const int* flag){
  int i = blockIdx.x*blockDim.x + threadIdx.x;
  if (i < n) dst[i] = rdf(src, off + i, *flag);
}
__global__ void k_zero(float* p, int n){
  int i = blockIdx.x*blockDim.x + threadIdx.x;
  if (i < n) p[i] = 0.f;
}

// ---------------- weight swizzle into MFMA B-fragment order ----------------
// b-frag (ks, ct): lane l, elem j <- B[ks*32 + 8*(l>>4)+j][ct*16 + (l&15)]
// stored at dst[((ks*NCT + ct)*64 + l)*8 + j]
// mode 0: B = src1 [K,N] row-major. mode 1: GRU cat K=256,N=512 from Wih/Whh [384,128].
__global__ void k_swz(const void* s1, const void* s2, ushort* dst,
                      int K, int N, int mode, const int* flag){
  int total = (K/32)*(N/16)*512;
  int o = blockIdx.x*blockDim.x + threadIdx.x;
  if (o >= total) return;
  int nct = N/16;
  int ks = o / (nct*512);
  int r1 = o % (nct*512);
  int ct = r1 / 512;
  int r2 = r1 % 512;
  int l  = r2 >> 3;
  int j  = r2 & 7;
  int k  = ks*32 + ((l>>4)<<3) + j;
  int c  = ct*16 + (l&15);
  float v;
  int isbf = *flag;
  if (mode == 0){
    v = rdf(s1, (long)k*N + c, isbf);
  } else {
    if (k < HH){
      if (c < 3*HH) v = rdf(s1, (long)c*HH + k, isbf);               // r,z,i_n from Wih
      else          v = 0.f;                                          // h_n x-part
    } else {
      int kh = k - HH;
      if (c < 2*HH)      v = rdf(s2, (long)c*HH + kh, isbf);         // r,z from Whh
      else if (c < 3*HH) v = 0.f;                                     // i_n h-part
      else               v = rdf(s2, (long)(c-HH)*HH + kh, isbf);    // h_n from Whh
    }
  }
  dst[o] = f2bu(v);
}

// bias4[c]: c<256: bih[c]+bhh[c]; c<384: bih[c]; else bhh[c-128]
__global__ void k_bias4(const void* bih, const void* bhh, float* bias4, const int* flag){
  int c = blockIdx.x*blockDim.x + threadIdx.x;
  if (c >= 4*HH) return;
  int isbf = *flag;
  float v;
  if (c < 2*HH)      v = rdf(bih, c, isbf) + rdf(bhh, c, isbf);
  else if (c < 3*HH) v = rdf(bih, c, isbf);
  else               v = rdf(bhh, c - HH, isbf);
  bias4[c] = v;
}

// ---------------- fused GCN input: h0 = relu(x@W_in+b); out = h0@W1 ----------------
// grid (NB32, T_CHUNK), 256 threads. out = [tl][M_PAD][HH] bf16
__global__ __launch_bounds__(256) void k_gcn01(const void* xseq, int t0, const int* flag,
    const float* b_inF, const short8* B1, const short8* B2, ushort* out)
{
  __shared__ __align__(16) ushort As[32*64];
  __shared__ __align__(16) ushort Xs[32*128];
  const int tid = threadIdx.x;
  const int bm  = blockIdx.x*32;
  const int tl  = blockIdx.y;
  {
    int row = tid>>3, seg = tid&7;
    int grow = bm + row;
    int colu = seg*8;
    V8 r;
    if (grow < NN){
      long base = ((long)(t0+tl)*NN + grow)*FF + colu;
      if (*flag){
        r.v = *(const short8*)((const ushort*)xseq + base);
      } else {
        const f32x4* s = (const f32x4*)((const float*)xseq + base);
        f32x4 f0 = s[0], f1 = s[1];
        #pragma unroll
        for (int j=0;j<4;j++){ r.u[j]=f2bu(f0[j]); r.u[4+j]=f2bu(f1[j]); }
      }
    } else {
      #pragma unroll
      for (int j=0;j<8;j++) r.u[j] = 0;
    }
    *(short8*)&As[row*64 + (colu ^ ((row&7)<<3))] = r.v;
  }
  __syncthreads();
  const int w = tid>>6, l = tid&63;
  f32x4 acc[2][2];
  #pragma unroll
  for (int i=0;i<2;i++)
    #pragma unroll
    for (int j=0;j<2;j++) acc[i][j] = (f32x4){0.f,0.f,0.f,0.f};
  #pragma unroll
  for (int ks=0; ks<2; ks++){
    short8 a[2], b[2];
    #pragma unroll
    for (int rt=0;rt<2;rt++){
      int row = rt*16 + (l&15);
      int colu = ks*32 + ((l>>4)<<3);
      a[rt] = *reinterpret_cast<const short8*>(&As[row*64 + (colu ^ ((row&7)<<3))]);
    }
    #pragma unroll
    for (int c2=0;c2<2;c2++) b[c2] = B1[(ks*8 + w*2+c2)*64 + l];
    #pragma unroll
    for (int rt=0;rt<2;rt++)
      #pragma unroll
      for (int c2=0;c2<2;c2++)
        acc[rt][c2] = __builtin_amdgcn_mfma_f32_16x16x32_bf16(a[rt], b[c2], acc[rt][c2], 0,0,0);
  }
  // epilogue0 -> LDS (bias+relu)
  #pragma unroll
  for (int rt=0;rt<2;rt++)
    #pragma unroll
    for (int c2=0;c2<2;c2++){
      int col = w*32 + c2*16 + (l&15);
      #pragma unroll
      for (int reg=0;reg<4;reg++){
        int rl = rt*16 + ((l>>4)<<2) + reg;
        float v = fmaxf(acc[rt][c2][reg] + b_inF[col], 0.f);
        Xs[rl*128 + (col ^ ((rl&7)<<3))] = f2bu(v);
      }
    }
  __syncthreads();
  f32x4 acc1[2][2];
  #pragma unroll
  for (int i=0;i<2;i++)
    #pragma unroll
    for (int j=0;j<2;j++) acc1[i][j] = (f32x4){0.f,0.f,0.f,0.f};
  #pragma unroll
  for (int ks=0; ks<4; ks++){
    short8 a[2], b[2];
    #pragma unroll
    for (int rt=0;rt<2;rt++){
      int row = rt*16 + (l&15);
      int colu = ks*32 + ((l>>4)<<3);
      a[rt] = *reinterpret_cast<const short8*>(&Xs[row*128 + (colu ^ ((row&7)<<3))]);
    }
    #pragma unroll
    for (int c2=0;c2<2;c2++) b[c2] = B2[(ks*8 + w*2+c2)*64 + l];
    #pragma unroll
    for (int rt=0;rt<2;rt++)
      #pragma unroll
      for (int c2=0;c2<2;c2++)
        acc1[rt][c2] = __builtin_amdgcn_mfma_f32_16x16x32_bf16(a[rt], b[c2], acc1[rt][c2], 0,0,0);
  }
  ushort* o = out + (long)tl*M_PAD*HH;
  #pragma unroll
  for (int rt=0;rt<2;rt++)
    #pragma unroll
    for (int c2=0;c2<2;c2++){
      int col = w*32 + c2*16 + (l&15);
      #pragma unroll
      for (int reg=0;reg<4;reg++){
        int grow = bm + rt*16 + ((l>>4)<<2) + reg;
        o[(long)grow*HH + col] = f2bu(acc1[rt][c2][reg]);
      }
    }
}

// ---------------- batched GEMM2: out = (BN(A)+relu) @ W2 ----------------
// grid (NB32, T_CHUNK), 256 threads
__global__ __launch_bounds__(256) void k_mgemm2b(const ushort* Ain, const float* slots, int t0,
    const void* gw, const void* bew, const int* flag, const short8* B3, ushort* out)
{
  __shared__ __align__(16) ushort As[32*128];
  __shared__ float sc_s[HH], sh_s[HH];
  const int tid = threadIdx.x;
  const int bm  = blockIdx.x*32;
  const int tl  = blockIdx.y;
  const float* slot = slots + ((size_t)(t0+tl)*2 + 0)*2*HH;
  if (tid < HH){
    float mu  = slot[tid]*INVN;
    float var = fmaxf(slot[HH+tid]*INVN - mu*mu, 0.f);
    float sc  = rdf(gw, tid, *flag) * rsqrtf(var + BN_EPS);
    sc_s[tid] = sc;
    sh_s[tid] = rdf(bew, tid, *flag) - mu*sc;
  }
  __syncthreads();
  const ushort* A = Ain + (long)tl*M_PAD*HH;
  {
    int row = tid>>3, seg = tid&7;
    int grow = bm + row;
    #pragma unroll
    for (int i=0;i<2;i++){
      int colu = seg*16 + i*8;
      V8 a; a.v = *(const short8*)(A + (long)grow*HH + colu);
      V8 r;
      #pragma unroll
      for (int j=0;j<8;j++){
        int k = colu + j;
        r.u[j] = f2bu(fmaxf(bu2f(a.u[j])*sc_s[k] + sh_s[k], 0.f));
      }
      *(short8*)&As[row*128 + (colu ^ ((row&7)<<3))] = r.v;
    }
  }
  __syncthreads();
  const int w = tid>>6, l = tid&63;
  f32x4 acc[2][2];
  #pragma unroll
  for (int i=0;i<2;i++)
    #pragma unroll
    for (int j=0;j<2;j++) acc[i][j] = (f32x4){0.f,0.f,0.f,0.f};
  #pragma unroll
  for (int ks=0; ks<4; ks++){
    short8 a[2], b[2];
    #pragma unroll
    for (int rt=0;rt<2;rt++){
      int row = rt*16 + (l&15);
      int colu = ks*32 + ((l>>4)<<3);
      a[rt] = *reinterpret_cast<const short8*>(&As[row*128 + (colu ^ ((row&7)<<3))]);
    }
    #pragma unroll
    for (int c2=0;c2<2;c2++) b[c2] = B3[(ks*8 + w*2+c2)*64 + l];
    #pragma unroll
    for (int rt=0;rt<2;rt++)
      #pragma unroll
      for (int c2=0;c2<2;c2++)
        acc[rt][c2] = __builtin_amdgcn_mfma_f32_16x16x32_bf16(a[rt], b[c2], acc[rt][c2], 0,0,0);
  }
  ushort* o = out + (long)tl*M_PAD*HH;
  #pragma unroll
  for (int rt=0;rt<2;rt++)
    #pragma unroll
    for (int c2=0;c2<2;c2++){
      int col = w*32 + c2*16 + (l&15);
      #pragma unroll
      for (int reg=0;reg<4;reg++){
        int grow = bm + rt*16 + ((l>>4)<<2) + reg;
        o[(long)grow*HH + col] = f2bu(acc[rt][c2][reg]);
      }
    }
}

// ---------------- fused double GRU step ----------------
// grid (NB32), 512 threads (8 waves). Block: 32 rows, full 128 h-cols, both layers.
__global__ __launch_bounds__(512) void k_gru2(const ushort* agg, const float* slots, int t,
    const void* gw, const void* bew, const int* flag,
    const float* h0prev, const float* h1prev,
    const short8* BG0, const short8* BG1,
    const float* bias4_0, const float* bias4_1,
    float* h0out, float* h1out)
{
  __shared__ __align__(16) ushort As[32*256];
  __shared__ float sc_s[HH], sh_s[HH];
  const int tid = threadIdx.x;
  const int bm  = blockIdx.x*32;
  const float* slot = slots + ((size_t)t*2 + 1)*2*HH;
  if (tid < HH){
    float mu  = slot[tid]*INVN;
    float var = fmaxf(slot[HH+tid]*INVN - mu*mu, 0.f);
    float sc  = rdf(gw, tid, *flag) * rsqrtf(var + BN_EPS);
    sc_s[tid] = sc;
    sh_s[tid] = rdf(bew, tid, *flag) - mu*sc;
  }
  __syncthreads();
  // stage layer-0 A: cols 0-127 = BN(agg)+relu, cols 128-255 = h0prev
  {
    int row = tid>>4, seg = tid&15;
    int grow = bm + row;
    #pragma unroll
    for (int i=0;i<2;i++){
      int colu = seg*16 + i*8;
      V8 r;
      if (colu < 128){
        V8 a; a.v = *(const short8*)(agg + (long)grow*HH + colu);
        #pragma unroll
        for (int j=0;j<8;j++){
          int k = colu + j;
          r.u[j] = f2bu(fmaxf(bu2f(a.u[j])*sc_s[k] + sh_s[k], 0.f));
        }
      } else {
        const f32x4* s = (const f32x4*)(h0prev + (long)grow*HH + (colu-128));
        f32x4 f0 = s[0], f1 = s[1];
        #pragma unroll
        for (int j=0;j<4;j++){ r.u[j]=f2bu(f0[j]); r.u[4+j]=f2bu(f1[j]); }
      }
      *(short8*)&As[row*256 + (colu ^ ((row&7)<<3))] = r.v;
    }
  }
  __syncthreads();
  const int w = tid>>6, l = tid&63;   // 8 waves; wave w -> h-cols [w*16, w*16+16)
  const int col = w*16 + (l&15);
  f32x4 acc[2][4];
  #pragma unroll
  for (int i=0;i<2;i++)
    #pragma unroll
    for (int g=0;g<4;g++) acc[i][g] = (f32x4){0.f,0.f,0.f,0.f};
  #pragma unroll
  for (int ks=0; ks<8; ks++){
    short8 a[2];
    #pragma unroll
    for (int rt=0;rt<2;rt++){
      int row = rt*16 + (l&15);
      int colu = ks*32 + ((l>>4)<<3);
      a[rt] = *reinterpret_cast<const short8*>(&As[row*256 + (colu ^ ((row&7)<<3))]);
    }
    #pragma unroll
    for (int g=0;g<4;g++){
      short8 b = BG0[(ks*32 + g*8 + w)*64 + l];
      acc[0][g] = __builtin_amdgcn_mfma_f32_16x16x32_bf16(a[0], b, acc[0][g], 0,0,0);
      acc[1][g] = __builtin_amdgcn_mfma_f32_16x16x32_bf16(a[1], b, acc[1][g], 0,0,0);
    }
  }
  __syncthreads();    // all layer-0 reads of As complete
  // epilogue0: h0_new -> global + LDS cols 0-127
  {
    float br = bias4_0[col], bz = bias4_0[HH+col], bi = bias4_0[2*HH+col], bh = bias4_0[3*HH+col];
    #pragma unroll
    for (int rt=0;rt<2;rt++)
      #pragma unroll
      for (int reg=0;reg<4;reg++){
        int rl = rt*16 + ((l>>4)<<2) + reg;
        int grow = bm + rl;
        float r = 1.f/(1.f + expf(-(acc[rt][0][reg] + br)));
        float z = 1.f/(1.f + expf(-(acc[rt][1][reg] + bz)));
        float nc = tanhf(acc[rt][2][reg] + bi + r*(acc[rt][3][reg] + bh));
        float hv = h0prev[(long)grow*HH + col];
        float hn = (1.f - z)*nc + z*hv;
        h0out[(long)grow*HH + col] = hn;
        As[rl*256 + (col ^ ((rl&7)<<3))] = f2bu(hn);
      }
  }
  // stage h1prev into cols 128-255
  {
    int row = tid>>4, seg = tid&15;
    if (seg >= 8){
      int grow = bm + row;
      #pragma unroll
      for (int i=0;i<2;i++){
        int colu = seg*16 + i*8;                      // 128..255
        const f32x4* s = (const f32x4*)(h1prev + (long)grow*HH + (colu-128));
        f32x4 f0 = s[0], f1 = s[1];
        V8 r;
        #pragma unroll
        for (int j=0;j<4;j++){ r.u[j]=f2bu(f0[j]); r.u[4+j]=f2bu(f1[j]); }
        *(short8*)&As[row*256 + (colu ^ ((row&7)<<3))] = r.v;
      }
    }
  }
  __syncthreads();
  // layer 1
  f32x4 acc1[2][4];
  #pragma unroll
  for (int i=0;i<2;i++)
    #pragma unroll
    for (int g=0;g<4;g++) acc1[i][g] = (f32x4){0.f,0.f,0.f,0.f};
  #pragma unroll
  for (int ks=0; ks<8; ks++){
    short8 a[2];
    #pragma unroll
    for (int rt=0;rt<2;rt++){
      int row = rt*16 + (l&15);
      int colu = ks*32 + ((l>>4)<<3);
      a[rt] = *reinterpret_cast<const short8*>(&As[row*256 + (colu ^ ((row&7)<<3))]);
    }
    #pragma unroll
    for (int g=0;g<4;g++){
      short8 b = BG1[(ks*32 + g*8 + w)*64 + l];
      acc1[0][g] = __builtin_amdgcn_mfma_f32_16x16x32_bf16(a[0], b, acc1[0][g], 0,0,0);
      acc1[1][g] = __builtin_amdgcn_mfma_f32_16x16x32_bf16(a[1], b, acc1[1][g], 0,0,0);
    }
  }
  // epilogue1: h1_new -> global
  {
    float br = bias4_1[col], bz = bias4_1[HH+col], bi = bias4_1[2*HH+col], bh = bias4_1[3*HH+col];
    #pragma unroll
    for (int rt=0;rt<2;rt++)
      #pragma unroll
      for (int reg=0;reg<4;reg++){
        int rl = rt*16 + ((l>>4)<<2) + reg;
        int grow = bm + rl;
        float r = 1.f/(1.f + expf(-(acc1[rt][0][reg] + br)));
        float z = 1.f/(1.f + expf(-(acc1[rt][1][reg] + bz)));
        float nc = tanhf(acc1[rt][2][reg] + bi + r*(acc1[rt][3][reg] + bh));
        float hv = h1prev[(long)grow*HH + col];
        h1out[(long)grow*HH + col] = (1.f - z)*nc + z*hv;
      }
  }
}

// ---------------- conv (CSR gather): 2 nodes/block (one per wave), uint loads ----------------
__global__ __launch_bounds__(128) void k_conv(const ushort* inb, ushort* outb,
    const int* offs, const int* csr_src, const float* csr_norm, const float* selfn)
{
  const int tl = blockIdx.y;
  const ushort* in  = inb  + (long)tl*M_PAD*HH;
  ushort* out = outb + (long)tl*M_PAD*HH;
  int n = blockIdx.x*2 + (threadIdx.x>>6);
  int l = threadIdx.x & 63;
  int c = l*2;
  uint v = *(const uint*)(in + (long)n*HH + c);
  float sn = selfn[n];
  float ax = sn * bu2f((ushort)(v & 0xffff));
  float ay = sn * bu2f((ushort)(v >> 16));
  int e0 = offs[n], e1 = offs[n+1];
  int e = e0;
  for (; e + 1 < e1; e += 2){
    int   s0 = csr_src[e],   s1 = csr_src[e+1];
    float w0 = csr_norm[e],  w1 = csr_norm[e+1];
    uint u0 = *(const uint*)(in + (long)s0*HH + c);
    uint u1 = *(const uint*)(in + (long)s1*HH + c);
    ax += w0*bu2f((ushort)(u0 & 0xffff)) + w1*bu2f((ushort)(u1 & 0xffff));
    ay += w0*bu2f((ushort)(u0 >> 16))    + w1*bu2f((ushort)(u1 >> 16));
  }
  if (e < e1){
    int s0 = csr_src[e]; float w0 = csr_norm[e];
    uint u0 = *(const uint*)(in + (long)s0*HH + c);
    ax += w0*bu2f((ushort)(u0 & 0xffff));
    ay += w0*bu2f((ushort)(u0 >> 16));
  }
  uint o = (uint)f2bu(ax) | ((uint)f2bu(ay) << 16);
  *(uint*)(out + (long)n*HH + c) = o;
}

// ---------------- BN stats into slot (t0+tl, layer) ----------------
__global__ __launch_bounds__(256) void k_bnstats(const ushort* xb, float* slots, int t0, int layer){
  const int tl = blockIdx.y;
  const ushort* x = xb + (long)tl*M_PAD*HH;
  float* slot = slots + ((size_t)(t0+tl)*2 + layer)*2*HH;
  int h = threadIdx.x & 127;
  int g = threadIdx.x >> 7;
  float s = 0.f, ss = 0.f;
  for (int r = blockIdx.x*2 + g; r < NN; r += gridDim.x*2){
    float v = bu2f(x[(long)r*HH + h]);
    s += v; ss += v*v;
  }
  __shared__ float sh[2][HH], shq[2][HH];
  sh[g][h] = s; shq[g][h] = ss;
  __syncthreads();
  if (g == 0){
    atomicAdd(&slot[h],    sh[0][h] + sh[1][h]);
    atomicAdd(&slot[HH+h], shq[0][h] + shq[1][h]);
  }
}

// ---------------- output head ----------------
__global__ void k_out(const float* h, const float* Wo, const float* bo, void* out, int n,
                      const int* flag){
  __shared__ float Ws[HH][CC+1];
  __shared__ float bs[CC];
  int tid = threadIdx.x;
  for (int i = tid; i < HH*CC; i += 256) Ws[i/CC][i%CC] = Wo[i];
  if (tid < CC) bs[tid] = bo[tid];
  __syncthreads();
  int row = blockIdx.x*16 + (tid >> 4);
  int c   = tid & 15;
  if (row >= n) return;
  const float* hr = h + (size_t)row*HH;
  float s = bs[c];
  #pragma unroll 8
  for (int j = 0; j < HH; j++) s += hr[j]*Ws[j][c];
  float m = s;
  for (int o = 8; o; o >>= 1) m = fmaxf(m, __shfl_xor(m, o, 16));
  float e = expf(s - m);
  float sum = e;
  for (int o = 8; o; o >>= 1) sum += __shfl_xor(sum, o, 16);
  float v = s - m - logf(sum);
  size_t idx = (size_t)row*CC + c;
  if (*flag) ((bf16*)out)[idx] = __float2bfloat16(v);
  else       ((float*)out)[idx] = v;
}

// ---------------- launcher ----------------
static inline size_t alignup(size_t x){ return (x + 255) & ~(size_t)255; }
static inline int ceil_div(int a, int b){ return (a + b - 1)/b; }

extern "C" void kernel_launch(void* const* d_in, const int* in_sizes, int n_in,
                              void* d_out, int out_size, void* d_ws, size_t ws_size,
                              hipStream_t stream){
  const void* x_seq = d_in[0];
  const int*  eidx  = (const int*)d_in[1];
  const void* ew    = d_in[2];
  const void* W_in  = d_in[3];
  const void* b_in  = d_in[4];
  const void* W1    = d_in[5];
  // d_in[6] = bc1 : cancels under training-mode BN
  const void* g1    = d_in[7];
  const void* be1   = d_in[8];
  const void* W2    = d_in[9];
  // d_in[10] = bc2 : cancels under BN
  const void* g2    = d_in[11];
  const void* be2   = d_in[12];
  const void* Wih0  = d_in[13];
  const void* Whh0  = d_in[14];
  const void* bih0  = d_in[15];
  const void* bhh0  = d_in[16];
  const void* Wih1  = d_in[17];
  const void* Whh1  = d_in[18];
  const void* bih1  = d_in[19];
  const void* bhh1  = d_in[20];
  const void* W_out = d_in[21];
  const void* b_out = d_in[22];
  const int* src = eidx;
  const int* dst = eidx + EE;

  // workspace (~110 MB)
  char* p = (char*)d_ws;
  auto alloc = [&](size_t bytes)->void*{ void* r = (void*)p; p += alignup(bytes); return r; };
  int*   flag     = (int*)  alloc(4);
  float* deg      = (float*)alloc(NN*4);
  float* dinv     = (float*)alloc(NN*4);
  float* selfn    = (float*)alloc(NN*4);
  int*   cnt      = (int*)  alloc(NN*4);
  int*   cursor   = (int*)  alloc(NN*4);
  int*   offs     = (int*)  alloc((NN+1)*4);
  int*   csr_src  = (int*)  alloc((size_t)EE*4);
  float* csr_norm = (float*)alloc((size_t)EE*4);
  ushort* B1sw  = (ushort*)alloc((size_t)(FF/32)*(HH/16)*512*2);      // 16 KB
  ushort* B2sw  = (ushort*)alloc((size_t)(HH/32)*(HH/16)*512*2);      // 32 KB
  ushort* B3sw  = (ushort*)alloc((size_t)(HH/32)*(HH/16)*512*2);
  ushort* BG0sw = (ushort*)alloc((size_t)8*32*512*2);                 // 256 KB
  ushort* BG1sw = (ushort*)alloc((size_t)8*32*512*2);
  float* bias4_0 = (float*)alloc(4*HH*4);
  float* bias4_1 = (float*)alloc(4*HH*4);
  float* b_inF   = (float*)alloc(HH*4);
  float* W_outF  = (float*)alloc(HH*CC*4);
  float* b_outF  = (float*)alloc(CC*4);
  float* slots   = (float*)alloc((size_t)T_STEPS*2*2*HH*4);           // 64 KB
  ushort* temp2b = (ushort*)alloc((size_t)T_CHUNK*M_PAD*HH*2);        // 20.5 MB
  ushort* agg1b  = (ushort*)alloc((size_t)T_CHUNK*M_PAD*HH*2);
  ushort* agg2b  = (ushort*)alloc((size_t)T_CHUNK*M_PAD*HH*2);
  float*  h0bufA = (float*)alloc((size_t)M_PAD*HH*4);                 // 10.26 MB
  float*  h0bufB = (float*)alloc((size_t)M_PAD*HH*4);
  float*  h1bufA = (float*)alloc((size_t)M_PAD*HH*4);
  float*  h1bufB = (float*)alloc((size_t)M_PAD*HH*4);
  (void)ws_size; (void)n_in; (void)in_sizes; (void)out_size;

  const int TPB = 256;
  // ---- dtype probe + graph setup ----
  k_detect<<<1, 256, 0, stream>>>(x_seq, flag);
  k_init<<<ceil_div(NN,TPB), TPB, 0, stream>>>(deg, cnt, cursor, NN);
  k_deg <<<ceil_div(EE,TPB), TPB, 0, stream>>>(src, dst, ew, deg, cnt, EE, flag);
  k_dinv<<<ceil_div(NN,TPB), TPB, 0, stream>>>(deg, dinv, selfn, NN);
  k_scan<<<1, 256, 0, stream>>>(cnt, offs, NN);
  k_fill<<<ceil_div(EE,TPB), TPB, 0, stream>>>(src, dst, ew, dinv, offs, cursor, csr_src, csr_norm, EE, flag);

  // ---- weight prep ----
  k_swz<<<ceil_div(2*8*512,TPB), TPB, 0, stream>>>(W_in, nullptr, B1sw, FF, HH, 0, flag);
  k_swz<<<ceil_div(4*8*512,TPB), TPB, 0, stream>>>(W1,   nullptr, B2sw, HH, HH, 0, flag);
  k_swz<<<ceil_div(4*8*512,TPB), TPB, 0, stream>>>(W2,   nullptr, B3sw, HH, HH, 0, flag);
  k_swz<<<ceil_div(8*32*512,TPB), TPB, 0, stream>>>(Wih0, Whh0, BG0sw, 2*HH, 4*HH, 1, flag);
  k_swz<<<ceil_div(8*32*512,TPB), TPB, 0, stream>>>(Wih1, Whh1, BG1sw, 2*HH, 4*HH, 1, flag);
  k_bias4<<<2, 256, 0, stream>>>(bih0, bhh0, bias4_0, flag);
  k_bias4<<<2, 256, 0, stream>>>(bih1, bhh1, bias4_1, flag);
  k_cvt<<<1, 128, 0, stream>>>(b_in, 0, b_inF, HH, flag);
  k_cvt<<<ceil_div(HH*CC,TPB), TPB, 0, stream>>>(W_out, 0, W_outF, HH*CC, flag);
  k_cvt<<<1, CC, 0, stream>>>(b_out, 0, b_outF, CC, flag);
  int totH = M_PAD*HH;
  k_zero<<<ceil_div(totH,TPB), TPB, 0, stream>>>(h0bufA, totH);
  k_zero<<<ceil_div(totH,TPB), TPB, 0, stream>>>(h1bufA, totH);
  k_zero<<<ceil_div(T_STEPS*2*2*HH,TPB), TPB, 0, stream>>>(slots, T_STEPS*2*2*HH);

  float* H0[2] = {h0bufA, h0bufB};
  float* H1[2] = {h1bufA, h1bufB};
  int cur = 0;

  // ---- main loop: 4 chunks of 4 timesteps ----
  for (int c = 0; c < NCHUNK; c++){
    int t0 = c*T_CHUNK;
    dim3 gg(NB32, T_CHUNK);
    dim3 gc(NN/2, T_CHUNK);
    dim3 gb(128, T_CHUNK);
    k_gcn01 <<<gg, 256, 0, stream>>>(x_seq, t0, flag, b_inF, (const short8*)B1sw, (const short8*)B2sw, temp2b);
    k_conv  <<<gc, 128, 0, stream>>>(temp2b, agg1b, offs, csr_src, csr_norm, selfn);
    k_bnstats<<<gb, 256, 0, stream>>>(agg1b, slots, t0, 0);
    k_mgemm2b<<<gg, 256, 0, stream>>>(agg1b, slots, t0, g1, be1, flag, (const short8*)B3sw, temp2b);
    k_conv  <<<gc, 128, 0, stream>>>(temp2b, agg2b, offs, csr_src, csr_norm, selfn);
    k_bnstats<<<gb, 256, 0, stream>>>(agg2b, slots, t0, 1);
    for (int tt = 0; tt < T_CHUNK; tt++){
      int t = t0 + tt;
      int nxt = cur ^ 1;
      k_gru2<<<NB32, 512, 0, stream>>>(agg2b + (size_t)tt*M_PAD*HH, slots, t,
                                       g2, be2, flag, H0[cur], H1[cur],
                                       (const short8*)BG0sw, (const short8*)BG1sw,
                                       bias4_0, bias4_1, H0[nxt], H1[nxt]);
      cur = nxt;
    }
  }

  // ---- output head ----
  k_out<<<ceil_div(NN,16), 256, 0, stream>>>(H1[cur], W_outF, b_outF, d_out, NN, flag);
}

// Round 8
// 1747.934 us; speedup vs baseline: 8.5682x; 1.2000x over previous
//
#include <hip/hip_runtime.h>
#include <hip/hip_bf16.h>
#include <stdint.h>

#define T_STEPS 16
#define T_CHUNK 4
#define NCHUNK  4
#define NN      20000
#define M_PAD   20032     // 626 * 32
#define NB32    626
#define EE      640000
#define FF      64
#define HH      128
#define CC      16
#define BN_EPS  1e-5f
#define INVN    (1.0f/(float)NN)
#define RS      (T_CHUNK*HH)        // row stride in tl-inner layout

typedef __hip_bfloat16 bf16;
typedef unsigned long long ull;
typedef __attribute__((ext_vector_type(8))) short short8;
typedef __attribute__((ext_vector_type(4))) float f32x4;

union V8 { short8 v; ushort u[8]; };

__device__ __forceinline__ float rdf(const void* p, long i, int isbf){
  return isbf ? __bfloat162float(((const bf16*)p)[i]) : ((const float*)p)[i];
}
__device__ __forceinline__ ushort f2bu(float f){
  bf16 h = __float2bfloat16(f);
  return *reinterpret_cast<ushort*>(&h);
}
__device__ __forceinline__ float bu2f(ushort u){
  return __uint_as_float((uint)u << 16);
}
__device__ __forceinline__ float blo(uint u){ return __uint_as_float(u << 16); }
__device__ __forceinline__ float bhi(uint u){ return __uint_as_float(u & 0xffff0000u); }

// ---------------- dtype probe (flag=1 iff buffers are bf16) ----------------
__global__ void k_detect(const void* x, int* flag){
  __shared__ int sh[256];
  int tid = threadIdx.x;
  const uint16_t* u = (const uint16_t*)x;
  uint16_t v = u[2*tid];
  int e = (v >> 7) & 0xFF;
  sh[tid] = (e >= 120 && e <= 134) ? 1 : 0;
  __syncthreads();
  for (int o = 128; o; o >>= 1){ if (tid < o) sh[tid] += sh[tid+o]; __syncthreads(); }
  if (tid == 0) flag[0] = (sh[0] >= 128) ? 1 : 0;
}

// ---------------- graph setup ----------------
// deg64: low 32 = Q20 fixed-point weighted degree (init 1<<20 = self-loop), high 32 = count
__global__ void k_init(ull* deg64, int* cursor, int n){
  int i = blockIdx.x*blockDim.x + threadIdx.x;
  if (i < n){ deg64[i] = (ull)(1u<<20); cursor[i] = 0; }
}
__global__ void k_deg(const int* dst, const void* w, ull* deg64, int e, const int* flag){
  int i = blockIdx.x*blockDim.x + threadIdx.x;
  if (i < e){
    float wv = rdf(w, i, *flag);
    ull pk = (1ULL<<32) | (ull)(uint)(wv*1048576.0f + 0.5f);
    atomicAdd(&deg64[dst[i]], pk);
  }
}
__global__ void k_dinv(const ull* deg64, float* dinv, float* selfnorm, int* cnt, int n){
  int i = blockIdx.x*blockDim.x + threadIdx.x;
  if (i < n){
    ull v = deg64[i];
    float d = (float)(uint)(v & 0xffffffffULL) * (1.0f/1048576.0f);
    cnt[i] = (int)(v >> 32);
    float r = d > 0.f ? rsqrtf(d) : 0.f;
    dinv[i] = r; selfnorm[i] = r*r;
  }
}
__global__ void k_scan(const int* cnt, int* offs, int n){
  __shared__ int part[256];
  int tid = threadIdx.x;
  int chunk = (n + 255)/256;
  int lo = tid*chunk; int hi = lo + chunk;
  if (hi > n) hi = n;
  if (lo > n) lo = n;
  int s = 0;
  for (int i = lo; i < hi; i++) s += cnt[i];
  part[tid] = s;
  __syncthreads();
  for (int off = 1; off < 256; off <<= 1){
    int t = (tid >= off) ? part[tid-off] : 0;
    __syncthreads();
    part[tid] += t;
    __syncthreads();
  }
  int run = part[tid] - s;
  for (int i = lo; i < hi; i++){ offs[i] = run; run += cnt[i]; }
  if (tid == 255) offs[n] = part[255];
}
__global__ void k_fill(const int* src, const int* dst, const void* w, const float* dinv,
                       const int* offs, int* cursor, int* csr_src, float* csr_norm, int e,
                       const int* flag){
  int i = blockIdx.x*blockDim.x + threadIdx.x;
  if (i < e){
    int s = src[i], d = dst[i];
    int pos = offs[d] + atomicAdd(&cursor[d], 1);
    csr_src[pos]  = s;
    csr_norm[pos] = dinv[s] * rdf(w, i, *flag) * dinv[d];
  }
}

__global__ void k_cvt(const void* src, long off, float* dst, int n, const int* flag){
  int i = blockIdx.x*blockDim.x + threadIdx.x;
  if (i < n) dst[i] = rdf(src, off + i, *flag);
}
__global__ void k_zero(float* p, int n){
  int i = blockIdx.x*blockDim.x + threadIdx.x;
  if (i < n) p[i] = 0.f;
}

// ---------------- weight swizzle into MFMA B-fragment order ----------------
// b-frag (ks, ct): lane l, elem j <- B[ks*32 + 8*(l>>4)+j][ct*16 + (l&15)]
// mode 0: B = src1 [K,N] row-major. mode 1: GRU cat K=256,N=512 from Wih/Whh [384,128].
__global__ void k_swz(const void* s1, const void* s2, ushort* dst,
                      int K, int N, int mode, const int* flag){
  int total = (K/32)*(N/16)*512;
  int o = blockIdx.x*blockDim.x + threadIdx.x;
  if (o >= total) return;
  int nct = N/16;
  int ks = o / (nct*512);
  int r1 = o % (nct*512);
  int ct = r1 / 512;
  int r2 = r1 % 512;
  int l  = r2 >> 3;
  int j  = r2 & 7;
  int k  = ks*32 + ((l>>4)<<3) + j;
  int c  = ct*16 + (l&15);
  float v;
  int isbf = *flag;
  if (mode == 0){
    v = rdf(s1, (long)k*N + c, isbf);
  } else {
    if (k < HH){
      if (c < 3*HH) v = rdf(s1, (long)c*HH + k, isbf);               // r,z,i_n from Wih
      else          v = 0.f;                                          // h_n x-part
    } else {
      int kh = k - HH;
      if (c < 2*HH)      v = rdf(s2, (long)c*HH + kh, isbf);         // r,z from Whh
      else if (c < 3*HH) v = 0.f;                                     // i_n h-part
      else               v = rdf(s2, (long)(c-HH)*HH + kh, isbf);    // h_n from Whh
    }
  }
  dst[o] = f2bu(v);
}

// bias4[c]: c<256: bih[c]+bhh[c]; c<384: bih[c]; else bhh[c-128]
__global__ void k_bias4(const void* bih, const void* bhh, float* bias4, const int* flag){
  int c = blockIdx.x*blockDim.x + threadIdx.x;
  if (c >= 4*HH) return;
  int isbf = *flag;
  float v;
  if (c < 2*HH)      v = rdf(bih, c, isbf) + rdf(bhh, c, isbf);
  else if (c < 3*HH) v = rdf(bih, c, isbf);
  else               v = rdf(bhh, c - HH, isbf);
  bias4[c] = v;
}

// ---------------- fused GCN input: h0 = relu(x@W_in+b); out = h0@W1 ----------------
// grid (NB32, T_CHUNK), 256 threads. out layout [node][T_CHUNK][HH] bf16
__global__ __launch_bounds__(256) void k_gcn01(const void* xseq, int t0, const int* flag,
    const float* b_inF, const short8* B1, const short8* B2, ushort* out)
{
  __shared__ __align__(16) ushort As[32*64];
  __shared__ __align__(16) ushort Xs[32*128];
  const int tid = threadIdx.x;
  const int bm  = blockIdx.x*32;
  const int tl  = blockIdx.y;
  {
    int row = tid>>3, seg = tid&7;
    int grow = bm + row;
    int colu = seg*8;
    V8 r;
    if (grow < NN){
      long base = ((long)(t0+tl)*NN + grow)*FF + colu;
      if (*flag){
        r.v = *(const short8*)((const ushort*)xseq + base);
      } else {
        const f32x4* s = (const f32x4*)((const float*)xseq + base);
        f32x4 f0 = s[0], f1 = s[1];
        #pragma unroll
        for (int j=0;j<4;j++){ r.u[j]=f2bu(f0[j]); r.u[4+j]=f2bu(f1[j]); }
      }
    } else {
      #pragma unroll
      for (int j=0;j<8;j++) r.u[j] = 0;
    }
    *(short8*)&As[row*64 + (colu ^ ((row&7)<<3))] = r.v;
  }
  __syncthreads();
  const int w = tid>>6, l = tid&63;
  f32x4 acc[2][2];
  #pragma unroll
  for (int i=0;i<2;i++)
    #pragma unroll
    for (int j=0;j<2;j++) acc[i][j] = (f32x4){0.f,0.f,0.f,0.f};
  #pragma unroll
  for (int ks=0; ks<2; ks++){
    short8 a[2], b[2];
    #pragma unroll
    for (int rt=0;rt<2;rt++){
      int row = rt*16 + (l&15);
      int colu = ks*32 + ((l>>4)<<3);
      a[rt] = *reinterpret_cast<const short8*>(&As[row*64 + (colu ^ ((row&7)<<3))]);
    }
    #pragma unroll
    for (int c2=0;c2<2;c2++) b[c2] = B1[(ks*8 + w*2+c2)*64 + l];
    #pragma unroll
    for (int rt=0;rt<2;rt++)
      #pragma unroll
      for (int c2=0;c2<2;c2++)
        acc[rt][c2] = __builtin_amdgcn_mfma_f32_16x16x32_bf16(a[rt], b[c2], acc[rt][c2], 0,0,0);
  }
  // epilogue0 -> LDS (bias+relu)
  #pragma unroll
  for (int rt=0;rt<2;rt++)
    #pragma unroll
    for (int c2=0;c2<2;c2++){
      int col = w*32 + c2*16 + (l&15);
      #pragma unroll
      for (int reg=0;reg<4;reg++){
        int rl = rt*16 + ((l>>4)<<2) + reg;
        float v = fmaxf(acc[rt][c2][reg] + b_inF[col], 0.f);
        Xs[rl*128 + (col ^ ((rl&7)<<3))] = f2bu(v);
      }
    }
  __syncthreads();
  f32x4 acc1[2][2];
  #pragma unroll
  for (int i=0;i<2;i++)
    #pragma unroll
    for (int j=0;j<2;j++) acc1[i][j] = (f32x4){0.f,0.f,0.f,0.f};
  #pragma unroll
  for (int ks=0; ks<4; ks++){
    short8 a[2], b[2];
    #pragma unroll
    for (int rt=0;rt<2;rt++){
      int row = rt*16 + (l&15);
      int colu = ks*32 + ((l>>4)<<3);
      a[rt] = *reinterpret_cast<const short8*>(&Xs[row*128 + (colu ^ ((row&7)<<3))]);
    }
    #pragma unroll
    for (int c2=0;c2<2;c2++) b[c2] = B2[(ks*8 + w*2+c2)*64 + l];
    #pragma unroll
    for (int rt=0;rt<2;rt++)
      #pragma unroll
      for (int c2=0;c2<2;c2++)
        acc1[rt][c2] = __builtin_amdgcn_mfma_f32_16x16x32_bf16(a[rt], b[c2], acc1[rt][c2], 0,0,0);
  }
  #pragma unroll
  for (int rt=0;rt<2;rt++)
    #pragma unroll
    for (int c2=0;c2<2;c2++){
      int col = w*32 + c2*16 + (l&15);
      #pragma unroll
      for (int reg=0;reg<4;reg++){
        int grow = bm + rt*16 + ((l>>4)<<2) + reg;
        out[((long)grow*T_CHUNK + tl)*HH + col] = f2bu(acc1[rt][c2][reg]);
      }
    }
}

// ---------------- batched GEMM2: out = (BN(A)+relu) @ W2, tl-inner layout ----------------
__global__ __launch_bounds__(256) void k_mgemm2b(const ushort* Ain, const float* slots, int t0,
    const void* gw, const void* bew, const int* flag, const short8* B3, ushort* out)
{
  __shared__ __align__(16) ushort As[32*128];
  __shared__ float sc_s[HH], sh_s[HH];
  const int tid = threadIdx.x;
  const int bm  = blockIdx.x*32;
  const int tl  = blockIdx.y;
  const float* slot = slots + ((size_t)(t0+tl)*2 + 0)*2*HH;
  if (tid < HH){
    float mu  = slot[tid]*INVN;
    float var = fmaxf(slot[HH+tid]*INVN - mu*mu, 0.f);
    float sc  = rdf(gw, tid, *flag) * rsqrtf(var + BN_EPS);
    sc_s[tid] = sc;
    sh_s[tid] = rdf(bew, tid, *flag) - mu*sc;
  }
  __syncthreads();
  {
    int row = tid>>3, seg = tid&7;
    int grow = bm + row;
    #pragma unroll
    for (int i=0;i<2;i++){
      int colu = seg*16 + i*8;
      V8 a; a.v = *(const short8*)(Ain + ((long)grow*T_CHUNK + tl)*HH + colu);
      V8 r;
      #pragma unroll
      for (int j=0;j<8;j++){
        int k = colu + j;
        r.u[j] = f2bu(fmaxf(bu2f(a.u[j])*sc_s[k] + sh_s[k], 0.f));
      }
      *(short8*)&As[row*128 + (colu ^ ((row&7)<<3))] = r.v;
    }
  }
  __syncthreads();
  const int w = tid>>6, l = tid&63;
  f32x4 acc[2][2];
  #pragma unroll
  for (int i=0;i<2;i++)
    #pragma unroll
    for (int j=0;j<2;j++) acc[i][j] = (f32x4){0.f,0.f,0.f,0.f};
  #pragma unroll
  for (int ks=0; ks<4; ks++){
    short8 a[2], b[2];
    #pragma unroll
    for (int rt=0;rt<2;rt++){
      int row = rt*16 + (l&15);
      int colu = ks*32 + ((l>>4)<<3);
      a[rt] = *reinterpret_cast<const short8*>(&As[row*128 + (colu ^ ((row&7)<<3))]);
    }
    #pragma unroll
    for (int c2=0;c2<2;c2++) b[c2] = B3[(ks*8 + w*2+c2)*64 + l];
    #pragma unroll
    for (int rt=0;rt<2;rt++)
      #pragma unroll
      for (int c2=0;c2<2;c2++)
        acc[rt][c2] = __builtin_amdgcn_mfma_f32_16x16x32_bf16(a[rt], b[c2], acc[rt][c2], 0,0,0);
  }
  #pragma unroll
  for (int rt=0;rt<2;rt++)
    #pragma unroll
    for (int c2=0;c2<2;c2++){
      int col = w*32 + c2*16 + (l&15);
      #pragma unroll
      for (int reg=0;reg<4;reg++){
        int grow = bm + rt*16 + ((l>>4)<<2) + reg;
        out[((long)grow*T_CHUNK + tl)*HH + col] = f2bu(acc[rt][c2][reg]);
      }
    }
}

// ---------------- fused double GRU step (tl-inner agg input) ----------------
__global__ __launch_bounds__(512) void k_gru2(const ushort* agg, int tt, const float* slots, int t,
    const void* gw, const void* bew, const int* flag,
    const float* h0prev, const float* h1prev,
    const short8* BG0, const short8* BG1,
    const float* bias4_0, const float* bias4_1,
    float* h0out, float* h1out)
{
  __shared__ __align__(16) ushort As[32*256];
  __shared__ float sc_s[HH], sh_s[HH];
  const int tid = threadIdx.x;
  const int bm  = blockIdx.x*32;
  const float* slot = slots + ((size_t)t*2 + 1)*2*HH;
  if (tid < HH){
    float mu  = slot[tid]*INVN;
    float var = fmaxf(slot[HH+tid]*INVN - mu*mu, 0.f);
    float sc  = rdf(gw, tid, *flag) * rsqrtf(var + BN_EPS);
    sc_s[tid] = sc;
    sh_s[tid] = rdf(bew, tid, *flag) - mu*sc;
  }
  __syncthreads();
  // stage layer-0 A: cols 0-127 = BN(agg)+relu, cols 128-255 = h0prev
  {
    int row = tid>>4, seg = tid&15;
    int grow = bm + row;
    #pragma unroll
    for (int i=0;i<2;i++){
      int colu = seg*16 + i*8;
      V8 r;
      if (colu < 128){
        V8 a; a.v = *(const short8*)(agg + ((long)grow*T_CHUNK + tt)*HH + colu);
        #pragma unroll
        for (int j=0;j<8;j++){
          int k = colu + j;
          r.u[j] = f2bu(fmaxf(bu2f(a.u[j])*sc_s[k] + sh_s[k], 0.f));
        }
      } else {
        const f32x4* s = (const f32x4*)(h0prev + (long)grow*HH + (colu-128));
        f32x4 f0 = s[0], f1 = s[1];
        #pragma unroll
        for (int j=0;j<4;j++){ r.u[j]=f2bu(f0[j]); r.u[4+j]=f2bu(f1[j]); }
      }
      *(short8*)&As[row*256 + (colu ^ ((row&7)<<3))] = r.v;
    }
  }
  __syncthreads();
  const int w = tid>>6, l = tid&63;   // 8 waves; wave w -> h-cols [w*16, w*16+16)
  const int col = w*16 + (l&15);
  f32x4 acc[2][4];
  #pragma unroll
  for (int i=0;i<2;i++)
    #pragma unroll
    for (int g=0;g<4;g++) acc[i][g] = (f32x4){0.f,0.f,0.f,0.f};
  #pragma unroll
  for (int ks=0; ks<8; ks++){
    short8 a[2];
    #pragma unroll
    for (int rt=0;rt<2;rt++){
      int row = rt*16 + (l&15);
      int colu = ks*32 + ((l>>4)<<3);
      a[rt] = *reinterpret_cast<const short8*>(&As[row*256 + (colu ^ ((row&7)<<3))]);
    }
    #pragma unroll
    for (int g=0;g<4;g++){
      short8 b = BG0[(ks*32 + g*8 + w)*64 + l];
      acc[0][g] = __builtin_amdgcn_mfma_f32_16x16x32_bf16(a[0], b, acc[0][g], 0,0,0);
      acc[1][g] = __builtin_amdgcn_mfma_f32_16x16x32_bf16(a[1], b, acc[1][g], 0,0,0);
    }
  }
  __syncthreads();
  // epilogue0: h0_new -> global + LDS cols 0-127
  {
    float br = bias4_0[col], bz = bias4_0[HH+col], bi = bias4_0[2*HH+col], bh = bias4_0[3*HH+col];
    #pragma unroll
    for (int rt=0;rt<2;rt++)
      #pragma unroll
      for (int reg=0;reg<4;reg++){
        int rl = rt*16 + ((l>>4)<<2) + reg;
        int grow = bm + rl;
        float r = 1.f/(1.f + expf(-(acc[rt][0][reg] + br)));
        float z = 1.f/(1.f + expf(-(acc[rt][1][reg] + bz)));
        float nc = tanhf(acc[rt][2][reg] + bi + r*(acc[rt][3][reg] + bh));
        float hv = h0prev[(long)grow*HH + col];
        float hn = (1.f - z)*nc + z*hv;
        h0out[(long)grow*HH + col] = hn;
        As[rl*256 + (col ^ ((rl&7)<<3))] = f2bu(hn);
      }
  }
  // stage h1prev into cols 128-255
  {
    int row = tid>>4, seg = tid&15;
    if (seg >= 8){
      int grow = bm + row;
      #pragma unroll
      for (int i=0;i<2;i++){
        int colu = seg*16 + i*8;                      // 128..255
        const f32x4* s = (const f32x4*)(h1prev + (long)grow*HH + (colu-128));
        f32x4 f0 = s[0], f1 = s[1];
        V8 r;
        #pragma unroll
        for (int j=0;j<4;j++){ r.u[j]=f2bu(f0[j]); r.u[4+j]=f2bu(f1[j]); }
        *(short8*)&As[row*256 + (colu ^ ((row&7)<<3))] = r.v;
      }
    }
  }
  __syncthreads();
  // layer 1
  f32x4 acc1[2][4];
  #pragma unroll
  for (int i=0;i<2;i++)
    #pragma unroll
    for (int g=0;g<4;g++) acc1[i][g] = (f32x4){0.f,0.f,0.f,0.f};
  #pragma unroll
  for (int ks=0; ks<8; ks++){
    short8 a[2];
    #pragma unroll
    for (int rt=0;rt<2;rt++){
      int row = rt*16 + (l&15);
      int colu = ks*32 + ((l>>4)<<3);
      a[rt] = *reinterpret_cast<const short8*>(&As[row*256 + (colu ^ ((row&7)<<3))]);
    }
    #pragma unroll
    for (int g=0;g<4;g++){
      short8 b = BG1[(ks*32 + g*8 + w)*64 + l];
      acc1[0][g] = __builtin_amdgcn_mfma_f32_16x16x32_bf16(a[0], b, acc1[0][g], 0,0,0);
      acc1[1][g] = __builtin_amdgcn_mfma_f32_16x16x32_bf16(a[1], b, acc1[1][g], 0,0,0);
    }
  }
  // epilogue1: h1_new -> global
  {
    float br = bias4_1[col], bz = bias4_1[HH+col], bi = bias4_1[2*HH+col], bh = bias4_1[3*HH+col];
    #pragma unroll
    for (int rt=0;rt<2;rt++)
      #pragma unroll
      for (int reg=0;reg<4;reg++){
        int rl = rt*16 + ((l>>4)<<2) + reg;
        int grow = bm + rl;
        float r = 1.f/(1.f + expf(-(acc1[rt][0][reg] + br)));
        float z = 1.f/(1.f + expf(-(acc1[rt][1][reg] + bz)));
        float nc = tanhf(acc1[rt][2][reg] + bi + r*(acc1[rt][3][reg] + bh));
        float hv = h1prev[(long)grow*HH + col];
        h1out[(long)grow*HH + col] = (1.f - z)*nc + z*hv;
      }
  }
}

// ---------------- conv (CSR gather), tl-inner: block = node, wave = tl ----------------
// in/out layout [node][T_CHUNK][HH]. 4 waves share one CSR stream; each edge -> 1KB contiguous.
__global__ __launch_bounds__(256) void k_conv(const ushort* in, ushort* out,
    const int* offs, const int* csr_src, const float* csr_norm, const float* selfn)
{
  const int n = blockIdx.x;
  const int w = threadIdx.x >> 6;       // tl
  const int c = (threadIdx.x & 63)*2;
  const ushort* base = in + (long)w*HH + c;
  uint v = *(const uint*)(base + (long)n*RS);
  float sn = selfn[n];
  float ax = sn * blo(v);
  float ay = sn * bhi(v);
  int e0 = offs[n], e1 = offs[n+1];
  int e = e0;
  for (; e + 1 < e1; e += 2){
    int   s0 = csr_src[e],   s1 = csr_src[e+1];
    float w0 = csr_norm[e],  w1 = csr_norm[e+1];
    uint u0 = *(const uint*)(base + (long)s0*RS);
    uint u1 = *(const uint*)(base + (long)s1*RS);
    ax += w0*blo(u0) + w1*blo(u1);
    ay += w0*bhi(u0) + w1*bhi(u1);
  }
  if (e < e1){
    int s0 = csr_src[e]; float w0 = csr_norm[e];
    uint u0 = *(const uint*)(base + (long)s0*RS);
    ax += w0*blo(u0);
    ay += w0*bhi(u0);
  }
  uint o = (uint)f2bu(ax) | ((uint)f2bu(ay) << 16);
  *(uint*)(out + (long)n*RS + (long)w*HH + c) = o;
}

// ---------------- BN stats into slot (t0+tl, layer), tl-inner layout ----------------
__global__ __launch_bounds__(256) void k_bnstats(const ushort* x, float* slots, int t0, int layer){
  const int tl = blockIdx.y;
  float* slot = slots + ((size_t)(t0+tl)*2 + layer)*2*HH;
  int h = threadIdx.x & 127;
  int g = threadIdx.x >> 7;
  float s = 0.f, ss = 0.f;
  for (int r = blockIdx.x*2 + g; r < NN; r += gridDim.x*2){
    float v = bu2f(x[((long)r*T_CHUNK + tl)*HH + h]);
    s += v; ss += v*v;
  }
  __shared__ float sh[2][HH], shq[2][HH];
  sh[g][h] = s; shq[g][h] = ss;
  __syncthreads();
  if (g == 0){
    atomicAdd(&slot[h],    sh[0][h] + sh[1][h]);
    atomicAdd(&slot[HH+h], shq[0][h] + shq[1][h]);
  }
}

// ---------------- output head ----------------
__global__ void k_out(const float* h, const float* Wo, const float* bo, void* out, int n,
                      const int* flag){
  __shared__ float Ws[HH][CC+1];
  __shared__ float bs[CC];
  int tid = threadIdx.x;
  for (int i = tid; i < HH*CC; i += 256) Ws[i/CC][i%CC] = Wo[i];
  if (tid < CC) bs[tid] = bo[tid];
  __syncthreads();
  int row = blockIdx.x*16 + (tid >> 4);
  int c   = tid & 15;
  if (row >= n) return;
  const float* hr = h + (size_t)row*HH;
  float s = bs[c];
  #pragma unroll 8
  for (int j = 0; j < HH; j++) s += hr[j]*Ws[j][c];
  float m = s;
  for (int o = 8; o; o >>= 1) m = fmaxf(m, __shfl_xor(m, o, 16));
  float e = expf(s - m);
  float sum = e;
  for (int o = 8; o; o >>= 1) sum += __shfl_xor(sum, o, 16);
  float v = s - m - logf(sum);
  size_t idx = (size_t)row*CC + c;
  if (*flag) ((bf16*)out)[idx] = __float2bfloat16(v);
  else       ((float*)out)[idx] = v;
}

// ---------------- launcher ----------------
static inline size_t alignup(size_t x){ return (x + 255) & ~(size_t)255; }
static inline int ceil_div(int a, int b){ return (a + b - 1)/b; }

extern "C" void kernel_launch(void* const* d_in, const int* in_sizes, int n_in,
                              void* d_out, int out_size, void* d_ws, size_t ws_size,
                              hipStream_t stream){
  const void* x_seq = d_in[0];
  const int*  eidx  = (const int*)d_in[1];
  const void* ew    = d_in[2];
  const void* W_in  = d_in[3];
  const void* b_in  = d_in[4];
  const void* W1    = d_in[5];
  // d_in[6] = bc1 : cancels under training-mode BN
  const void* g1    = d_in[7];
  const void* be1   = d_in[8];
  const void* W2    = d_in[9];
  // d_in[10] = bc2 : cancels under BN
  const void* g2    = d_in[11];
  const void* be2   = d_in[12];
  const void* Wih0  = d_in[13];
  const void* Whh0  = d_in[14];
  const void* bih0  = d_in[15];
  const void* bhh0  = d_in[16];
  const void* Wih1  = d_in[17];
  const void* Whh1  = d_in[18];
  const void* bih1  = d_in[19];
  const void* bhh1  = d_in[20];
  const void* W_out = d_in[21];
  const void* b_out = d_in[22];
  const int* src = eidx;
  const int* dst = eidx + EE;

  // workspace (~110 MB)
  char* p = (char*)d_ws;
  auto alloc = [&](size_t bytes)->void*{ void* r = (void*)p; p += alignup(bytes); return r; };
  int*   flag     = (int*)  alloc(4);
  ull*   deg64    = (ull*)  alloc((size_t)NN*8);
  float* dinv     = (float*)alloc(NN*4);
  float* selfn    = (float*)alloc(NN*4);
  int*   cnt      = (int*)  alloc(NN*4);
  int*   cursor   = (int*)  alloc(NN*4);
  int*   offs     = (int*)  alloc((NN+1)*4);
  int*   csr_src  = (int*)  alloc((size_t)EE*4);
  float* csr_norm = (float*)alloc((size_t)EE*4);
  ushort* B1sw  = (ushort*)alloc((size_t)(FF/32)*(HH/16)*512*2);      // 16 KB
  ushort* B2sw  = (ushort*)alloc((size_t)(HH/32)*(HH/16)*512*2);      // 32 KB
  ushort* B3sw  = (ushort*)alloc((size_t)(HH/32)*(HH/16)*512*2);
  ushort* BG0sw = (ushort*)alloc((size_t)8*32*512*2);                 // 256 KB
  ushort* BG1sw = (ushort*)alloc((size_t)8*32*512*2);
  float* bias4_0 = (float*)alloc(4*HH*4);
  float* bias4_1 = (float*)alloc(4*HH*4);
  float* b_inF   = (float*)alloc(HH*4);
  float* W_outF  = (float*)alloc(HH*CC*4);
  float* b_outF  = (float*)alloc(CC*4);
  float* slots   = (float*)alloc((size_t)T_STEPS*2*2*HH*4);           // 64 KB
  ushort* temp2b = (ushort*)alloc((size_t)M_PAD*T_CHUNK*HH*2);        // 20.5 MB
  ushort* agg1b  = (ushort*)alloc((size_t)M_PAD*T_CHUNK*HH*2);
  ushort* agg2b  = (ushort*)alloc((size_t)M_PAD*T_CHUNK*HH*2);
  float*  h0bufA = (float*)alloc((size_t)M_PAD*HH*4);                 // 10.26 MB
  float*  h0bufB = (float*)alloc((size_t)M_PAD*HH*4);
  float*  h1bufA = (float*)alloc((size_t)M_PAD*HH*4);
  float*  h1bufB = (float*)alloc((size_t)M_PAD*HH*4);
  (void)ws_size; (void)n_in; (void)in_sizes; (void)out_size;

  const int TPB = 256;
  // ---- dtype probe + graph setup ----
  k_detect<<<1, 256, 0, stream>>>(x_seq, flag);
  k_init<<<ceil_div(NN,TPB), TPB, 0, stream>>>(deg64, cursor, NN);
  k_deg <<<ceil_div(EE,TPB), TPB, 0, stream>>>(dst, ew, deg64, EE, flag);
  k_dinv<<<ceil_div(NN,TPB), TPB, 0, stream>>>(deg64, dinv, selfn, cnt, NN);
  k_scan<<<1, 256, 0, stream>>>(cnt, offs, NN);
  k_fill<<<ceil_div(EE,TPB), TPB, 0, stream>>>(src, dst, ew, dinv, offs, cursor, csr_src, csr_norm, EE, flag);

  // ---- weight prep ----
  k_swz<<<ceil_div(2*8*512,TPB), TPB, 0, stream>>>(W_in, nullptr, B1sw, FF, HH, 0, flag);
  k_swz<<<ceil_div(4*8*512,TPB), TPB, 0, stream>>>(W1,   nullptr, B2sw, HH, HH, 0, flag);
  k_swz<<<ceil_div(4*8*512,TPB), TPB, 0, stream>>>(W2,   nullptr, B3sw, HH, HH, 0, flag);
  k_swz<<<ceil_div(8*32*512,TPB), TPB, 0, stream>>>(Wih0, Whh0, BG0sw, 2*HH, 4*HH, 1, flag);
  k_swz<<<ceil_div(8*32*512,TPB), TPB, 0, stream>>>(Wih1, Whh1, BG1sw, 2*HH, 4*HH, 1, flag);
  k_bias4<<<2, 256, 0, stream>>>(bih0, bhh0, bias4_0, flag);
  k_bias4<<<2, 256, 0, stream>>>(bih1, bhh1, bias4_1, flag);
  k_cvt<<<1, 128, 0, stream>>>(b_in, 0, b_inF, HH, flag);
  k_cvt<<<ceil_div(HH*CC,TPB), TPB, 0, stream>>>(W_out, 0, W_outF, HH*CC, flag);
  k_cvt<<<1, CC, 0, stream>>>(b_out, 0, b_outF, CC, flag);
  int totH = M_PAD*HH;
  k_zero<<<ceil_div(totH,TPB), TPB, 0, stream>>>(h0bufA, totH);
  k_zero<<<ceil_div(totH,TPB), TPB, 0, stream>>>(h1bufA, totH);
  k_zero<<<ceil_div(T_STEPS*2*2*HH,TPB), TPB, 0, stream>>>(slots, T_STEPS*2*2*HH);

  float* H0[2] = {h0bufA, h0bufB};
  float* H1[2] = {h1bufA, h1bufB};
  int cur = 0;

  // ---- main loop: 4 chunks of 4 timesteps ----
  for (int c = 0; c < NCHUNK; c++){
    int t0 = c*T_CHUNK;
    dim3 gg(NB32, T_CHUNK);
    dim3 gb(128, T_CHUNK);
    k_gcn01 <<<gg, 256, 0, stream>>>(x_seq, t0, flag, b_inF, (const short8*)B1sw, (const short8*)B2sw, temp2b);
    k_conv  <<<NN, 256, 0, stream>>>(temp2b, agg1b, offs, csr_src, csr_norm, selfn);
    k_bnstats<<<gb, 256, 0, stream>>>(agg1b, slots, t0, 0);
    k_mgemm2b<<<gg, 256, 0, stream>>>(agg1b, slots, t0, g1, be1, flag, (const short8*)B3sw, temp2b);
    k_conv  <<<NN, 256, 0, stream>>>(temp2b, agg2b, offs, csr_src, csr_norm, selfn);
    k_bnstats<<<gb, 256, 0, stream>>>(agg2b, slots, t0, 1);
    for (int tt = 0; tt < T_CHUNK; tt++){
      int t = t0 + tt;
      int nxt = cur ^ 1;
      k_gru2<<<NB32, 512, 0, stream>>>(agg2b, tt, slots, t,
                                       g2, be2, flag, H0[cur], H1[cur],
                                       (const short8*)BG0sw, (const short8*)BG1sw,
                                       bias4_0, bias4_1, H0[nxt], H1[nxt]);
      cur = nxt;
    }
  }

  // ---- output head ----
  k_out<<<ceil_div(NN,16), 256, 0, stream>>>(H1[cur], W_outF, b_outF, d_out, NN, flag);
}